// Round 3
// baseline (880.432 us; speedup 1.0000x reference)
//
#include <hip/hip_runtime.h>

typedef unsigned short ushortT;
typedef __attribute__((ext_vector_type(8))) short short8;
typedef __attribute__((ext_vector_type(4))) float float4v;

__device__ __forceinline__ float bf2f(unsigned short h) {
    unsigned u = ((unsigned)h) << 16;
    return __builtin_bit_cast(float, u);
}
__device__ __forceinline__ unsigned short f2bf(float f) {
    unsigned u = __builtin_bit_cast(unsigned, f);
    u = u + 0x7fffu + ((u >> 16) & 1u);
    return (unsigned short)(u >> 16);
}
__device__ __forceinline__ void unpack_add(uint4 v, float a[8]) {
    a[0] += bf2f((ushortT)v.x); a[1] += bf2f((ushortT)(v.x >> 16));
    a[2] += bf2f((ushortT)v.y); a[3] += bf2f((ushortT)(v.y >> 16));
    a[4] += bf2f((ushortT)v.z); a[5] += bf2f((ushortT)(v.z >> 16));
    a[6] += bf2f((ushortT)v.w); a[7] += bf2f((ushortT)(v.w >> 16));
}

// 8-element row load; f32 flag folds at compile time
__device__ __forceinline__ void loadc8(bool f32, const void* p, size_t off, float o[8]) {
    if (f32) {
        const float* q = (const float*)p + off;
        float4 a = *(const float4*)q;
        float4 b = *(const float4*)(q + 4);
        o[0] = a.x; o[1] = a.y; o[2] = a.z; o[3] = a.w;
        o[4] = b.x; o[5] = b.y; o[6] = b.z; o[7] = b.w;
    } else {
        uint4 v = *(const uint4*)((const ushortT*)p + off);
        unsigned uu[4] = {v.x, v.y, v.z, v.w};
        #pragma unroll
        for (int j = 0; j < 8; j++) o[j] = bf2f((unsigned short)(uu[j >> 1] >> ((j & 1) * 16)));
    }
}

// ---------------- combined weight build: Wc[n][seg*512+g*128+dl | 4*DIN+d] ----------------
__global__ __launch_bounds__(256) void build_wc(const float* __restrict__ Ws, const float* __restrict__ Wb,
                                                ushortT* __restrict__ Wc, int dout, int din) {
    int idx = blockIdx.x * 256 + threadIdx.x;
    int kw = 5 * din;
    if (idx >= dout * kw) return;
    int n = idx / kw, c = idx % kw;
    float v;
    if (c < 4 * din) {
        int seg = c >> 9;
        int rem = c & 511;
        int g = rem >> 7;
        int dl = rem & 127;
        v = Ws[(size_t)n * 4 * din + 4 * (seg * 128 + dl) + g];
    } else {
        v = Wb[(size_t)n * din + (c - 4 * din)];
    }
    Wc[idx] = f2bf(v);
}

// ---------------- per-row LN stats for f32 x (+ optional bf16 mirror) ----------------

__global__ __launch_bounds__(256) void stats_f32(const float* __restrict__ X, float2* __restrict__ ST,
                                                 ushortT* __restrict__ xb, int n) {
    int wid = (blockIdx.x * 256 + threadIdx.x) >> 6;
    int lane = threadIdx.x & 63;
    if (wid >= n) return;
    float2 v = *(const float2*)(X + (size_t)wid * 128 + lane * 2);
    if (xb) {
        unsigned pk = (unsigned)f2bf(v.x) | ((unsigned)f2bf(v.y) << 16);
        *(unsigned*)(xb + (size_t)wid * 128 + lane * 2) = pk;
    }
    float s = v.x + v.y, ss = v.x * v.x + v.y * v.y;
    #pragma unroll
    for (int d = 1; d < 64; d <<= 1) { s += __shfl_xor(s, d); ss += __shfl_xor(ss, d); }
    if (lane == 0) ST[wid] = make_float2(s, ss);
}

// ---------------- CSR build: two-level counting sort ----------------
// Pack: src (bits 0..23, N < 2^24) | (dst & 255) << 24. Coarse bucket = dst >> 8.

__global__ __launch_bounds__(256) void zero_ints(int* p, int n) {
    int i = blockIdx.x * 256 + threadIdx.x;
    if (i < n) p[i] = 0;
}

__device__ __forceinline__ int wave_incl_scan(int v, int lane) {
    #pragma unroll
    for (int d = 1; d < 64; d <<= 1) {
        int o = __shfl_up(v, d);
        if (lane >= d) v += o;
    }
    return v;
}

// coarse histogram of dst>>8 (LDS-staged; ~nb global atomics per block)
__global__ __launch_bounds__(256) void coarse_hist(const int* __restrict__ dst, int* __restrict__ ghist,
                                                   int E, int nb) {
    __shared__ int h[512];
    for (int i = threadIdx.x; i < 512; i += 256) h[i] = 0;
    __syncthreads();
    int stride = gridDim.x * 256;
    for (int e = blockIdx.x * 256 + threadIdx.x; e < E; e += stride) {
        atomicAdd(&h[dst[e] >> 8], 1);
    }
    __syncthreads();
    for (int i = threadIdx.x; i < nb; i += 256) {
        int c = h[i];
        if (c) atomicAdd(&ghist[i], c);
    }
}

// exclusive scan of nb (<=512) bucket counts; writes base[0..nb] and a working copy gcur
__global__ __launch_bounds__(64) void bucket_scan(const int* __restrict__ ghist, int* __restrict__ base,
                                                  int* __restrict__ gcur, int nb) {
    int lane = threadIdx.x;
    int carry = 0;
    for (int b0 = 0; b0 < nb; b0 += 64) {
        int i = b0 + lane;
        int v = (i < nb) ? ghist[i] : 0;
        int incl = wave_incl_scan(v, lane);
        if (i < nb) { int ex = carry + incl - v; base[i] = ex; gcur[i] = ex; }
        carry += __shfl(incl, 63);
    }
    if (lane == 0) base[nb] = carry;
}

// bin edges into coarse buckets. Per block: LDS hist of its chunk, ONE global atomic per
// (block,bucket) to reserve a contiguous run, then LDS-cursor scatter -> runs of ~10 words.
#define SCAT_CH 4096
__global__ __launch_bounds__(256) void coarse_scatter(const int* __restrict__ src, const int* __restrict__ dst,
                                                      int* __restrict__ gcur, unsigned* __restrict__ pairs,
                                                      int E, int nb) {
    __shared__ int cur[512];
    for (int i = threadIdx.x; i < 512; i += 256) cur[i] = 0;
    __syncthreads();
    int e0 = blockIdx.x * SCAT_CH;
    int e1 = min(e0 + SCAT_CH, E);
    for (int e = e0 + threadIdx.x; e < e1; e += 256) atomicAdd(&cur[dst[e] >> 8], 1);
    __syncthreads();
    for (int i = threadIdx.x; i < nb; i += 256) {
        int c = cur[i];
        cur[i] = c ? atomicAdd(&gcur[i], c) : 0;
    }
    __syncthreads();
    for (int e = e0 + threadIdx.x; e < e1; e += 256) {
        int d = dst[e];
        int r = atomicAdd(&cur[d >> 8], 1);
        pairs[r] = (unsigned)src[e] | ((unsigned)(d & 255) << 24);
    }
}

// one block per coarse bucket: fine 256-bin hist -> rowptr + dinv, then scatter colv
// entirely inside the bucket's contiguous output window (full line utilization).
__global__ __launch_bounds__(256) void fine_csr(const unsigned* __restrict__ pairs, const int* __restrict__ base,
                                                int* __restrict__ rowptr, int* __restrict__ colv,
                                                float* __restrict__ dinv, int n, int E) {
    __shared__ int h[256];
    __shared__ int cur[256];
    __shared__ int wt[4];
    int b = blockIdx.x, tid = threadIdx.x;
    int e0 = base[b], e1 = base[b + 1];
    h[tid] = 0;
    __syncthreads();
    for (int e = e0 + tid; e < e1; e += 256) atomicAdd(&h[pairs[e] >> 24], 1);
    __syncthreads();
    int v = h[tid];
    int lane = tid & 63, w = tid >> 6;
    int incl = wave_incl_scan(v, lane);
    if (lane == 63) wt[w] = incl;
    __syncthreads();
    int woff = 0;
    for (int i = 0; i < w; i++) woff += wt[i];
    int excl = woff + incl - v;
    int node = b * 256 + tid;
    if (node < n) {
        rowptr[node] = e0 + excl;
        dinv[node] = rsqrtf((float)(v + 1));  // +1 self loop
        if (node == n - 1) rowptr[n] = E;
    }
    cur[tid] = e0 + excl;
    __syncthreads();
    for (int e = e0 + tid; e < e1; e += 256) {
        unsigned p = pairs[e];
        int r = atomicAdd(&cur[p >> 24], 1);
        colv[r] = (int)(p & 0x00FFFFFFu);
    }
}

// ---------------- fused FastKAN transform ----------------
// No LDS. ONE 16-row group per wave (64 rows/block) -> ~6.1 waves/SIMD at N=100k
// (was 3.05 with 128 rows/block; kernel is latency-bound at 25% occupancy).
// NOTE: f2bf bit-math only for bf16 packing — v_cvt_pk_bf16_f32 is NOT RTNE-equivalent
// (round-2 failure: systematic ~23-ulp accumulation over the 640-term K reduction).
// Output rows are PRE-SCALED by dinv[row] (for the gather that follows).
template <int NSEG, int DOUT, int F32MASK>
__global__ __launch_bounds__(256) void fkan_kernel(
    const void* __restrict__ X0, int s0,
    const void* __restrict__ X1, int s1,
    const void* __restrict__ X2, int s2,
    const float2* __restrict__ ST0, const float2* __restrict__ ST1, const float2* __restrict__ ST2,
    const float* __restrict__ lng, const float* __restrict__ lnb,
    const ushortT* __restrict__ Wc,
    const float* __restrict__ bs, const float* __restrict__ bb,
    const float* __restrict__ dinv,
    ushortT* __restrict__ H, int hstride, int nrows) {
    constexpr int DIN = NSEG * 128;
    constexpr int KW = 5 * DIN;
    constexpr int NT = (DOUT + 15) / 16;
    int tid = threadIdx.x;
    int w = tid >> 6, lane = tid & 63;
    int m = lane & 15, q = lane >> 4;
    int base = blockIdx.x * 64 + w * 16;
    int rA = min(base + m, nrows - 1);

    float muA, scA;
    {
        float2 st = ST0[rA]; float sum = st.x, ssq = st.y;
        if (NSEG == 3) { float2 t1 = ST1[rA]; sum += t1.x; ssq += t1.y; float2 t2 = ST2[rA]; sum += t2.x; ssq += t2.y; }
        muA = sum * (1.0f / DIN);
        float var = ssq * (1.0f / DIN) - muA * muA;
        scA = rsqrtf(fmaxf(var, 0.0f) + 1e-5f);
    }

    float4v acc[NT];
    #pragma unroll
    for (int t = 0; t < NT; t++) acc[t] = (float4v){0.f, 0.f, 0.f, 0.f};

    const float G[4] = {-2.f, -2.f / 3.f, 2.f / 3.f, 2.f};

    // ---- RBF region ----
    #pragma unroll
    for (int seg = 0; seg < NSEG; seg++) {
        const void* Xp = (seg == 0) ? X0 : (seg == 1) ? X1 : X2;
        int str = (seg == 0) ? s0 : (seg == 1) ? s1 : s2;
        bool f32 = ((F32MASK >> seg) & 1) != 0;
        #pragma unroll
        for (int i = 0; i < 4; i++) {
            int d0 = i * 32 + q * 8;
            float xa[8];
            loadc8(f32, Xp, (size_t)rA * str + d0, xa);
            float4 gv0 = *(const float4*)(lng + seg * 128 + d0);
            float4 gv1 = *(const float4*)(lng + seg * 128 + d0 + 4);
            float4 bv0 = *(const float4*)(lnb + seg * 128 + d0);
            float4 bv1 = *(const float4*)(lnb + seg * 128 + d0 + 4);
            float gvs[8] = {gv0.x, gv0.y, gv0.z, gv0.w, gv1.x, gv1.y, gv1.z, gv1.w};
            float bvs[8] = {bv0.x, bv0.y, bv0.z, bv0.w, bv1.x, bv1.y, bv1.z, bv1.w};
            float za[8];
            #pragma unroll
            for (int j = 0; j < 8; j++) {
                za[j] = (xa[j] - muA) * scA * gvs[j] + bvs[j];
            }
            #pragma unroll
            for (int g = 0; g < 4; g++) {
                short8 afa;
                #pragma unroll
                for (int j = 0; j < 8; j++) {
                    float da = (za[j] - G[g]) * 0.75f;
                    afa[j] = (short)f2bf(__expf(-da * da));
                }
                int kbase = seg * 512 + g * 128 + i * 32;
                #pragma unroll
                for (int t = 0; t < NT; t++) {
                    int n = t * 16 + m;
                    short8 bfr = (short8){0, 0, 0, 0, 0, 0, 0, 0};
                    if ((DOUT % 16 == 0) || (n < DOUT))
                        bfr = *(const short8*)(Wc + (size_t)n * KW + kbase + q * 8);
                    acc[t] = __builtin_amdgcn_mfma_f32_16x16x32_bf16(afa, bfr, acc[t], 0, 0, 0);
                }
            }
        }
    }

    // ---- SiLU region ----
    #pragma unroll
    for (int seg = 0; seg < NSEG; seg++) {
        const void* Xp = (seg == 0) ? X0 : (seg == 1) ? X1 : X2;
        int str = (seg == 0) ? s0 : (seg == 1) ? s1 : s2;
        bool f32 = ((F32MASK >> seg) & 1) != 0;
        #pragma unroll
        for (int i = 0; i < 4; i++) {
            int c = i * 32 + q * 8;
            float xa[8];
            loadc8(f32, Xp, (size_t)rA * str + c, xa);
            short8 afa;
            #pragma unroll
            for (int j = 0; j < 8; j++) {
                float sa = 1.0f / (1.0f + __expf(-xa[j]));
                afa[j] = (short)f2bf(xa[j] * sa);
            }
            int kbase = 4 * DIN + seg * 128 + i * 32;
            #pragma unroll
            for (int t = 0; t < NT; t++) {
                int n = t * 16 + m;
                short8 bfr = (short8){0, 0, 0, 0, 0, 0, 0, 0};
                if ((DOUT % 16 == 0) || (n < DOUT))
                    bfr = *(const short8*)(Wc + (size_t)n * KW + kbase + q * 8);
                acc[t] = __builtin_amdgcn_mfma_f32_16x16x32_bf16(afa, bfr, acc[t], 0, 0, 0);
            }
        }
    }

    // epilogue: C/D layout col=lane&15, row=quad*4+r ; store h*dinv[row]
    float dA[4];
    #pragma unroll
    for (int r = 0; r < 4; r++) {
        int rowA = base + q * 4 + r;
        dA[r] = (rowA < nrows) ? dinv[rowA] : 0.f;
    }
    #pragma unroll
    for (int t = 0; t < NT; t++) {
        int col = t * 16 + m;
        if ((DOUT % 16 == 0) || (col < DOUT)) {
            float bias = bs[col] + bb[col];
            #pragma unroll
            for (int r = 0; r < 4; r++) {
                int rowA = base + q * 4 + r;
                if (rowA < nrows) H[(size_t)rowA * hstride + col] = f2bf((acc[t][r] + bias) * dA[r]);
            }
        }
    }
}

// ---------------- aggregation: wave per node, 4 edges in flight ----------------
// H is pre-scaled by dinv[src]. out = dinv[wid]*(H[wid] + sum_nbr H[s]) + bg.

__global__ __launch_bounds__(256) void agg128_kernel(
    const ushortT* __restrict__ H, ushortT* __restrict__ OUT,
    const float* __restrict__ bg, const int* __restrict__ rowptr,
    const int* __restrict__ colv, const float* __restrict__ dinv,
    float2* __restrict__ STout, int n) {
    int wid = (blockIdx.x * 256 + threadIdx.x) >> 6;
    int lane = threadIdx.x & 63;
    if (wid >= n) return;
    int g = lane >> 4, t = lane & 15;
    float di = dinv[wid];
    float a[8] = {0.f, 0.f, 0.f, 0.f, 0.f, 0.f, 0.f, 0.f};
    if (g == 0) unpack_add(*(const uint4*)(H + (size_t)wid * 128 + t * 8), a);  // self
    int e0 = rowptr[wid], e1 = rowptr[wid + 1];
    for (int e = e0 + g; e < e1; e += 4) {
        int s = colv[e];
        unpack_add(*(const uint4*)(H + (size_t)s * 128 + t * 8), a);
    }
    #pragma unroll
    for (int j = 0; j < 8; j++) {
        a[j] += __shfl_xor(a[j], 16);
        a[j] += __shfl_xor(a[j], 32);
    }
    if (g == 0) {
        float4 b0 = *(const float4*)(bg + t * 8);
        float4 b1 = *(const float4*)(bg + t * 8 + 4);
        float bgs[8] = {b0.x, b0.y, b0.z, b0.w, b1.x, b1.y, b1.z, b1.w};
        unsigned rb[8];
        float s = 0.f, ss = 0.f;
        #pragma unroll
        for (int j = 0; j < 8; j++) {
            float o = di * a[j] + bgs[j];
            rb[j] = f2bf(o);
            float back = bf2f((unsigned short)rb[j]);
            s += back; ss += back * back;
        }
        uint4 pk;
        pk.x = rb[0] | (rb[1] << 16);
        pk.y = rb[2] | (rb[3] << 16);
        pk.z = rb[4] | (rb[5] << 16);
        pk.w = rb[6] | (rb[7] << 16);
        *(uint4*)(OUT + (size_t)wid * 128 + t * 8) = pk;
        #pragma unroll
        for (int d = 1; d < 16; d <<= 1) { s += __shfl_xor(s, d); ss += __shfl_xor(ss, d); }
        if (t == 0) STout[wid] = make_float2(s, ss);
    }
}

// H stride 64 (cols 47..63 junk, never written out). 8 edges in flight.
__global__ __launch_bounds__(256) void agg47_kernel(
    const ushortT* __restrict__ H, float* __restrict__ OUT,
    const float* __restrict__ bg, const int* __restrict__ rowptr,
    const int* __restrict__ colv, const float* __restrict__ dinv, int n) {
    int wid = (blockIdx.x * 256 + threadIdx.x) >> 6;
    int lane = threadIdx.x & 63;
    if (wid >= n) return;
    int g = lane >> 3, t = lane & 7;
    float di = dinv[wid];
    float a[8] = {0.f, 0.f, 0.f, 0.f, 0.f, 0.f, 0.f, 0.f};
    if (g == 0) unpack_add(*(const uint4*)(H + (size_t)wid * 64 + t * 8), a);  // self
    int e0 = rowptr[wid], e1 = rowptr[wid + 1];
    for (int e = e0 + g; e < e1; e += 8) {
        int s = colv[e];
        unpack_add(*(const uint4*)(H + (size_t)s * 64 + t * 8), a);
    }
    #pragma unroll
    for (int j = 0; j < 8; j++) {
        a[j] += __shfl_xor(a[j], 8);
        a[j] += __shfl_xor(a[j], 16);
        a[j] += __shfl_xor(a[j], 32);
    }
    if (g == 0) {
        #pragma unroll
        for (int j = 0; j < 8; j++) {
            int c = t * 8 + j;
            if (c < 47) OUT[(size_t)wid * 47 + c] = di * a[j] + bg[c];
        }
    }
}

// ---------------- launcher ----------------

extern "C" void kernel_launch(void* const* d_in, const int* in_sizes, int n_in,
                              void* d_out, int out_size, void* d_ws, size_t ws_size,
                              hipStream_t stream) {
    const float* x = (const float*)d_in[0];
    const int* ei = (const int*)d_in[1];
    const float* lng0 = (const float*)d_in[2];
    const float* lnb0 = (const float*)d_in[3];
    const float* Ws0 = (const float*)d_in[4];
    const float* bs0 = (const float*)d_in[5];
    const float* Wb0 = (const float*)d_in[6];
    const float* bb0 = (const float*)d_in[7];
    const float* bg0 = (const float*)d_in[8];
    const float* lng1 = (const float*)d_in[9];
    const float* lnb1 = (const float*)d_in[10];
    const float* Ws1 = (const float*)d_in[11];
    const float* bs1 = (const float*)d_in[12];
    const float* Wb1 = (const float*)d_in[13];
    const float* bb1 = (const float*)d_in[14];
    const float* bg1 = (const float*)d_in[15];
    const float* lng2 = (const float*)d_in[16];
    const float* lnb2 = (const float*)d_in[17];
    const float* Ws2 = (const float*)d_in[18];
    const float* bs2 = (const float*)d_in[19];
    const float* Wb2 = (const float*)d_in[20];
    const float* bb2 = (const float*)d_in[21];
    const float* bg2 = (const float*)d_in[22];

    const int N = in_sizes[0] / 128;
    const int E = in_sizes[1] / 2;
    const int NB = (N + 255) >> 8;  // coarse buckets of 256 nodes (requires N < 2^24)

    char* wsp = (char*)d_ws;
    size_t off = 0;
    auto alloc = [&](size_t bytes) {
        off = (off + 255) & ~(size_t)255;
        void* p = wsp + off;
        off += bytes;
        return p;
    };
    int* ghist = (int*)alloc(512 * 4);
    int* bbase = (int*)alloc(513 * 4);
    int* gcur = (int*)alloc(512 * 4);
    int* rowptr = (int*)alloc((size_t)(N + 1) * 4);
    int* colv = (int*)alloc((size_t)E * 4);
    float* dinvv = (float*)alloc((size_t)N * 4);
    ushortT* hbuf = (ushortT*)alloc((size_t)N * 128 * 2);
    ushortT* a1 = (ushortT*)alloc((size_t)N * 128 * 2);
    ushortT* a2 = (ushortT*)alloc((size_t)N * 128 * 2);
    float2* stx = (float2*)alloc((size_t)N * 8);
    float2* st1 = (float2*)alloc((size_t)N * 8);
    float2* st2 = (float2*)alloc((size_t)N * 8);
    ushortT* Wc0 = (ushortT*)alloc((size_t)128 * 640 * 2);
    ushortT* Wc1 = (ushortT*)alloc((size_t)128 * 640 * 2);
    ushortT* Wc2 = (ushortT*)alloc((size_t)47 * 1920 * 2);
    size_t off_base = off;
    ushortT* xb = (ushortT*)alloc((size_t)N * 128 * 2);  // bf16 mirror of x
    bool fits = (off <= ws_size);
    if (!fits) off = off_base;
    (void)n_in; (void)out_size;

    // pairs staging aliases hbuf: pairs is dead before the first fkan writes hbuf.
    unsigned* pairs = (unsigned*)hbuf;

    const int* srcp = ei;
    const int* dstp = ei + E;

    int gF = (N + 63) / 64;
    int gW = (N + 3) / 4;
    int gScat = (E + SCAT_CH - 1) / SCAT_CH;

    build_wc<<<(128 * 640 + 255) / 256, 256, 0, stream>>>(Ws0, Wb0, Wc0, 128, 128);
    build_wc<<<(128 * 640 + 255) / 256, 256, 0, stream>>>(Ws1, Wb1, Wc1, 128, 128);
    build_wc<<<(47 * 1920 + 255) / 256, 256, 0, stream>>>(Ws2, Wb2, Wc2, 47, 384);

    // CSR build: coarse hist -> scan -> coarse scatter (packed pairs) -> fine per-bucket CSR
    zero_ints<<<2, 256, 0, stream>>>(ghist, 512);
    coarse_hist<<<NB, 256, 0, stream>>>(dstp, ghist, E, NB);
    bucket_scan<<<1, 64, 0, stream>>>(ghist, bbase, gcur, NB);
    coarse_scatter<<<gScat, 256, 0, stream>>>(srcp, dstp, gcur, pairs, E, NB);
    fine_csr<<<NB, 256, 0, stream>>>(pairs, bbase, rowptr, colv, dinvv, N, E);

    stats_f32<<<gW, 256, 0, stream>>>(x, stx, fits ? xb : nullptr, N);

    // layer 1
    if (fits)
        fkan_kernel<1, 128, 0><<<gF, 256, 0, stream>>>(xb, 128, xb, 128, xb, 128, stx, stx, stx,
                                                       lng0, lnb0, Wc0, bs0, bb0, dinvv, hbuf, 128, N);
    else
        fkan_kernel<1, 128, 1><<<gF, 256, 0, stream>>>(x, 128, x, 128, x, 128, stx, stx, stx,
                                                       lng0, lnb0, Wc0, bs0, bb0, dinvv, hbuf, 128, N);
    agg128_kernel<<<gW, 256, 0, stream>>>(hbuf, a1, bg0, rowptr, colv, dinvv, st1, N);

    // layer 2
    fkan_kernel<1, 128, 0><<<gF, 256, 0, stream>>>(a1, 128, a1, 128, a1, 128, st1, st1, st1,
                                                   lng1, lnb1, Wc1, bs1, bb1, dinvv, hbuf, 128, N);
    agg128_kernel<<<gW, 256, 0, stream>>>(hbuf, a2, bg1, rowptr, colv, dinvv, st2, N);

    // layer 3 (hbuf stride 64)
    if (fits)
        fkan_kernel<3, 47, 0><<<gF, 256, 0, stream>>>(xb, 128, a1, 128, a2, 128, stx, st1, st2,
                                                      lng2, lnb2, Wc2, bs2, bb2, dinvv, hbuf, 64, N);
    else
        fkan_kernel<3, 47, 1><<<gF, 256, 0, stream>>>(x, 128, a1, 128, a2, 128, stx, st1, st2,
                                                      lng2, lnb2, Wc2, bs2, bb2, dinvv, hbuf, 64, N);
    agg47_kernel<<<gW, 256, 0, stream>>>(hbuf, (float*)d_out, bg2, rowptr, colv, dinvv, N);
}

// Round 4
// 729.558 us; speedup vs baseline: 1.2068x; 1.2068x over previous
//
#include <hip/hip_runtime.h>

typedef unsigned short ushortT;
typedef __attribute__((ext_vector_type(8))) short short8;
typedef __attribute__((ext_vector_type(4))) float float4v;

__device__ __forceinline__ float bf2f(unsigned short h) {
    unsigned u = ((unsigned)h) << 16;
    return __builtin_bit_cast(float, u);
}
__device__ __forceinline__ unsigned short f2bf(float f) {
    unsigned u = __builtin_bit_cast(unsigned, f);
    u = u + 0x7fffu + ((u >> 16) & 1u);
    return (unsigned short)(u >> 16);
}
__device__ __forceinline__ void unpack_add(uint4 v, float a[8]) {
    a[0] += bf2f((ushortT)v.x); a[1] += bf2f((ushortT)(v.x >> 16));
    a[2] += bf2f((ushortT)v.y); a[3] += bf2f((ushortT)(v.y >> 16));
    a[4] += bf2f((ushortT)v.z); a[5] += bf2f((ushortT)(v.z >> 16));
    a[6] += bf2f((ushortT)v.w); a[7] += bf2f((ushortT)(v.w >> 16));
}

// 8-element row load; f32 flag folds at compile time
__device__ __forceinline__ void loadc8(bool f32, const void* p, size_t off, float o[8]) {
    if (f32) {
        const float* q = (const float*)p + off;
        float4 a = *(const float4*)q;
        float4 b = *(const float4*)(q + 4);
        o[0] = a.x; o[1] = a.y; o[2] = a.z; o[3] = a.w;
        o[4] = b.x; o[5] = b.y; o[6] = b.z; o[7] = b.w;
    } else {
        uint4 v = *(const uint4*)((const ushortT*)p + off);
        unsigned uu[4] = {v.x, v.y, v.z, v.w};
        #pragma unroll
        for (int j = 0; j < 8; j++) o[j] = bf2f((unsigned short)(uu[j >> 1] >> ((j & 1) * 16)));
    }
}

// ---------------- combined weight build: Wc[n][seg*512+g*128+dl | 4*DIN+d] ----------------
__global__ __launch_bounds__(256) void build_wc(const float* __restrict__ Ws, const float* __restrict__ Wb,
                                                ushortT* __restrict__ Wc, int dout, int din) {
    int idx = blockIdx.x * 256 + threadIdx.x;
    int kw = 5 * din;
    if (idx >= dout * kw) return;
    int n = idx / kw, c = idx % kw;
    float v;
    if (c < 4 * din) {
        int seg = c >> 9;
        int rem = c & 511;
        int g = rem >> 7;
        int dl = rem & 127;
        v = Ws[(size_t)n * 4 * din + 4 * (seg * 128 + dl) + g];
    } else {
        v = Wb[(size_t)n * din + (c - 4 * din)];
    }
    Wc[idx] = f2bf(v);
}

// ---------------- per-row LN stats for f32 x (+ optional bf16 mirror) ----------------

__global__ __launch_bounds__(256) void stats_f32(const float* __restrict__ X, float2* __restrict__ ST,
                                                 ushortT* __restrict__ xb, int n) {
    int wid = (blockIdx.x * 256 + threadIdx.x) >> 6;
    int lane = threadIdx.x & 63;
    if (wid >= n) return;
    float2 v = *(const float2*)(X + (size_t)wid * 128 + lane * 2);
    if (xb) {
        unsigned pk = (unsigned)f2bf(v.x) | ((unsigned)f2bf(v.y) << 16);
        *(unsigned*)(xb + (size_t)wid * 128 + lane * 2) = pk;
    }
    float s = v.x + v.y, ss = v.x * v.x + v.y * v.y;
    #pragma unroll
    for (int d = 1; d < 64; d <<= 1) { s += __shfl_xor(s, d); ss += __shfl_xor(ss, d); }
    if (lane == 0) ST[wid] = make_float2(s, ss);
}

// ---------------- CSR build: two-level counting sort ----------------
// Pack: src (bits 0..23, N < 2^24) | (dst & 255) << 24. Coarse bucket = dst >> 8.

__global__ __launch_bounds__(256) void zero_ints(int* p, int n) {
    int i = blockIdx.x * 256 + threadIdx.x;
    if (i < n) p[i] = 0;
}

__device__ __forceinline__ int wave_incl_scan(int v, int lane) {
    #pragma unroll
    for (int d = 1; d < 64; d <<= 1) {
        int o = __shfl_up(v, d);
        if (lane >= d) v += o;
    }
    return v;
}

// coarse histogram of dst>>8 (LDS-staged; ~nb global atomics per block)
__global__ __launch_bounds__(256) void coarse_hist(const int* __restrict__ dst, int* __restrict__ ghist,
                                                   int E, int nb) {
    __shared__ int h[512];
    for (int i = threadIdx.x; i < 512; i += 256) h[i] = 0;
    __syncthreads();
    int stride = gridDim.x * 256;
    for (int e = blockIdx.x * 256 + threadIdx.x; e < E; e += stride) {
        atomicAdd(&h[dst[e] >> 8], 1);
    }
    __syncthreads();
    for (int i = threadIdx.x; i < nb; i += 256) {
        int c = h[i];
        if (c) atomicAdd(&ghist[i], c);
    }
}

// exclusive scan of nb (<=512) bucket counts; writes base[0..nb] and a working copy gcur
__global__ __launch_bounds__(64) void bucket_scan(const int* __restrict__ ghist, int* __restrict__ base,
                                                  int* __restrict__ gcur, int nb) {
    int lane = threadIdx.x;
    int carry = 0;
    for (int b0 = 0; b0 < nb; b0 += 64) {
        int i = b0 + lane;
        int v = (i < nb) ? ghist[i] : 0;
        int incl = wave_incl_scan(v, lane);
        if (i < nb) { int ex = carry + incl - v; base[i] = ex; gcur[i] = ex; }
        carry += __shfl(incl, 63);
    }
    if (lane == 0) base[nb] = carry;
}

// bin edges into coarse buckets. Per block: LDS hist of its chunk, ONE global atomic per
// (block,bucket) to reserve a contiguous run, then LDS-cursor scatter -> runs of ~10 words.
#define SCAT_CH 4096
__global__ __launch_bounds__(256) void coarse_scatter(const int* __restrict__ src, const int* __restrict__ dst,
                                                      int* __restrict__ gcur, unsigned* __restrict__ pairs,
                                                      int E, int nb) {
    __shared__ int cur[512];
    for (int i = threadIdx.x; i < 512; i += 256) cur[i] = 0;
    __syncthreads();
    int e0 = blockIdx.x * SCAT_CH;
    int e1 = min(e0 + SCAT_CH, E);
    for (int e = e0 + threadIdx.x; e < e1; e += 256) atomicAdd(&cur[dst[e] >> 8], 1);
    __syncthreads();
    for (int i = threadIdx.x; i < nb; i += 256) {
        int c = cur[i];
        cur[i] = c ? atomicAdd(&gcur[i], c) : 0;
    }
    __syncthreads();
    for (int e = e0 + threadIdx.x; e < e1; e += 256) {
        int d = dst[e];
        int r = atomicAdd(&cur[d >> 8], 1);
        pairs[r] = (unsigned)src[e] | ((unsigned)(d & 255) << 24);
    }
}

// one block per coarse bucket: fine 256-bin hist -> rowptr + dinv, then scatter colv
// entirely inside the bucket's contiguous output window (full line utilization).
__global__ __launch_bounds__(256) void fine_csr(const unsigned* __restrict__ pairs, const int* __restrict__ base,
                                                int* __restrict__ rowptr, int* __restrict__ colv,
                                                float* __restrict__ dinv, int n, int E) {
    __shared__ int h[256];
    __shared__ int cur[256];
    __shared__ int wt[4];
    int b = blockIdx.x, tid = threadIdx.x;
    int e0 = base[b], e1 = base[b + 1];
    h[tid] = 0;
    __syncthreads();
    for (int e = e0 + tid; e < e1; e += 256) atomicAdd(&h[pairs[e] >> 24], 1);
    __syncthreads();
    int v = h[tid];
    int lane = tid & 63, w = tid >> 6;
    int incl = wave_incl_scan(v, lane);
    if (lane == 63) wt[w] = incl;
    __syncthreads();
    int woff = 0;
    for (int i = 0; i < w; i++) woff += wt[i];
    int excl = woff + incl - v;
    int node = b * 256 + tid;
    if (node < n) {
        rowptr[node] = e0 + excl;
        dinv[node] = rsqrtf((float)(v + 1));  // +1 self loop
        if (node == n - 1) rowptr[n] = E;
    }
    cur[tid] = e0 + excl;
    __syncthreads();
    for (int e = e0 + tid; e < e1; e += 256) {
        unsigned p = pairs[e];
        int r = atomicAdd(&cur[p >> 24], 1);
        colv[r] = (int)(p & 0x00FFFFFFu);
    }
}

// ---------------- fused FastKAN transform ----------------
// Round-1 per-wave shape (2 row-groups sharing each Wc B-fragment, 2 ILP chains) PLUS
// K-split across waves: block = 64 rows, 4 waves = 2 row-panels x 2 K-halves.
// (Round-3 lesson: splitting ROWS per wave doubled Wc issue + halved ILP -> 45% slower.
//  K-split doubles occupancy while keeping both invariants; partial sums combined via LDS.)
// K-half assignment: (seg*4+i) parity == kk (wave-uniform branch, covers all chunks once).
// Epilogue split: kk=0 finalizes group A, kk=1 finalizes group B.
// Output rows PRE-SCALED by dinv[row]. f2bf bit-math only (round-2: v_cvt_pk != RTNE).
template <int NSEG, int DOUT, int F32MASK>
__global__ __launch_bounds__(256) void fkan_kernel(
    const void* __restrict__ X0, int s0,
    const void* __restrict__ X1, int s1,
    const void* __restrict__ X2, int s2,
    const float2* __restrict__ ST0, const float2* __restrict__ ST1, const float2* __restrict__ ST2,
    const float* __restrict__ lng, const float* __restrict__ lnb,
    const ushortT* __restrict__ Wc,
    const float* __restrict__ bs, const float* __restrict__ bb,
    const float* __restrict__ dinv,
    ushortT* __restrict__ H, int hstride, int nrows) {
    constexpr int DIN = NSEG * 128;
    constexpr int KW = 5 * DIN;
    constexpr int NT = (DOUT + 15) / 16;
    __shared__ float red[2][NT][4][64];  // [panel][tile][reg][lane]: 16KB @ NT=8
    int tid = threadIdx.x;
    int w = tid >> 6, lane = tid & 63;
    int m = lane & 15, q = lane >> 4;
    int r = w & 1;    // row panel
    int kk = w >> 1;  // K half
    int baseA = blockIdx.x * 64 + r * 16;
    int baseB = baseA + 32;
    int rA = min(baseA + m, nrows - 1);
    int rB = min(baseB + m, nrows - 1);

    float muA, scA, muB, scB;
    {
        float2 st = ST0[rA]; float sum = st.x, ssq = st.y;
        if (NSEG == 3) { float2 t1 = ST1[rA]; sum += t1.x; ssq += t1.y; float2 t2 = ST2[rA]; sum += t2.x; ssq += t2.y; }
        muA = sum * (1.0f / DIN);
        float var = ssq * (1.0f / DIN) - muA * muA;
        scA = rsqrtf(fmaxf(var, 0.0f) + 1e-5f);
    }
    {
        float2 st = ST0[rB]; float sum = st.x, ssq = st.y;
        if (NSEG == 3) { float2 t1 = ST1[rB]; sum += t1.x; ssq += t1.y; float2 t2 = ST2[rB]; sum += t2.x; ssq += t2.y; }
        muB = sum * (1.0f / DIN);
        float var = ssq * (1.0f / DIN) - muB * muB;
        scB = rsqrtf(fmaxf(var, 0.0f) + 1e-5f);
    }

    float4v acc[NT][2];
    #pragma unroll
    for (int t = 0; t < NT; t++) {
        acc[t][0] = (float4v){0.f, 0.f, 0.f, 0.f};
        acc[t][1] = (float4v){0.f, 0.f, 0.f, 0.f};
    }

    const float G[4] = {-2.f, -2.f / 3.f, 2.f / 3.f, 2.f};

    // ---- RBF region (this wave's K-half only) ----
    #pragma unroll
    for (int seg = 0; seg < NSEG; seg++) {
        const void* Xp = (seg == 0) ? X0 : (seg == 1) ? X1 : X2;
        int str = (seg == 0) ? s0 : (seg == 1) ? s1 : s2;
        bool f32 = ((F32MASK >> seg) & 1) != 0;
        #pragma unroll
        for (int i = 0; i < 4; i++) {
            if (((seg * 4 + i) & 1) != kk) continue;
            int d0 = i * 32 + q * 8;
            float xa[8], xb8[8];
            loadc8(f32, Xp, (size_t)rA * str + d0, xa);
            loadc8(f32, Xp, (size_t)rB * str + d0, xb8);
            float4 gv0 = *(const float4*)(lng + seg * 128 + d0);
            float4 gv1 = *(const float4*)(lng + seg * 128 + d0 + 4);
            float4 bv0 = *(const float4*)(lnb + seg * 128 + d0);
            float4 bv1 = *(const float4*)(lnb + seg * 128 + d0 + 4);
            float gvs[8] = {gv0.x, gv0.y, gv0.z, gv0.w, gv1.x, gv1.y, gv1.z, gv1.w};
            float bvs[8] = {bv0.x, bv0.y, bv0.z, bv0.w, bv1.x, bv1.y, bv1.z, bv1.w};
            float za[8], zb[8];
            #pragma unroll
            for (int j = 0; j < 8; j++) {
                za[j] = (xa[j] - muA) * scA * gvs[j] + bvs[j];
                zb[j] = (xb8[j] - muB) * scB * gvs[j] + bvs[j];
            }
            #pragma unroll
            for (int g = 0; g < 4; g++) {
                short8 afa, afb;
                #pragma unroll
                for (int j = 0; j < 8; j++) {
                    float da = (za[j] - G[g]) * 0.75f;
                    afa[j] = (short)f2bf(__expf(-da * da));
                    float db = (zb[j] - G[g]) * 0.75f;
                    afb[j] = (short)f2bf(__expf(-db * db));
                }
                int kbase = seg * 512 + g * 128 + i * 32;
                #pragma unroll
                for (int t = 0; t < NT; t++) {
                    int n = t * 16 + m;
                    short8 bfr = (short8){0, 0, 0, 0, 0, 0, 0, 0};
                    if ((DOUT % 16 == 0) || (n < DOUT))
                        bfr = *(const short8*)(Wc + (size_t)n * KW + kbase + q * 8);
                    acc[t][0] = __builtin_amdgcn_mfma_f32_16x16x32_bf16(afa, bfr, acc[t][0], 0, 0, 0);
                    acc[t][1] = __builtin_amdgcn_mfma_f32_16x16x32_bf16(afb, bfr, acc[t][1], 0, 0, 0);
                }
            }
        }
    }

    // ---- SiLU region (this wave's K-half only) ----
    #pragma unroll
    for (int seg = 0; seg < NSEG; seg++) {
        const void* Xp = (seg == 0) ? X0 : (seg == 1) ? X1 : X2;
        int str = (seg == 0) ? s0 : (seg == 1) ? s1 : s2;
        bool f32 = ((F32MASK >> seg) & 1) != 0;
        #pragma unroll
        for (int i = 0; i < 4; i++) {
            if (((seg * 4 + i) & 1) != kk) continue;
            int c = i * 32 + q * 8;
            float xa[8], xb8[8];
            loadc8(f32, Xp, (size_t)rA * str + c, xa);
            loadc8(f32, Xp, (size_t)rB * str + c, xb8);
            short8 afa, afb;
            #pragma unroll
            for (int j = 0; j < 8; j++) {
                float sa = 1.0f / (1.0f + __expf(-xa[j]));
                afa[j] = (short)f2bf(xa[j] * sa);
                float sb = 1.0f / (1.0f + __expf(-xb8[j]));
                afb[j] = (short)f2bf(xb8[j] * sb);
            }
            int kbase = 4 * DIN + seg * 128 + i * 32;
            #pragma unroll
            for (int t = 0; t < NT; t++) {
                int n = t * 16 + m;
                short8 bfr = (short8){0, 0, 0, 0, 0, 0, 0, 0};
                if ((DOUT % 16 == 0) || (n < DOUT))
                    bfr = *(const short8*)(Wc + (size_t)n * KW + kbase + q * 8);
                acc[t][0] = __builtin_amdgcn_mfma_f32_16x16x32_bf16(afa, bfr, acc[t][0], 0, 0, 0);
                acc[t][1] = __builtin_amdgcn_mfma_f32_16x16x32_bf16(afb, bfr, acc[t][1], 0, 0, 0);
            }
        }
    }

    // ---- cross-wave K-half reduction (2 barriers, self-ordered LDS reuse) ----
    if (kk == 1) {
        #pragma unroll
        for (int t = 0; t < NT; t++)
            #pragma unroll
            for (int j = 0; j < 4; j++) red[r][t][j][lane] = acc[t][0][j];
    }
    __syncthreads();
    if (kk == 0) {
        #pragma unroll
        for (int t = 0; t < NT; t++)
            #pragma unroll
            for (int j = 0; j < 4; j++) {
                acc[t][0][j] += red[r][t][j][lane];  // full group-A sum
                red[r][t][j][lane] = acc[t][1][j];   // hand B partial to the k=1 wave
            }
    }
    __syncthreads();
    if (kk == 1) {
        #pragma unroll
        for (int t = 0; t < NT; t++)
            #pragma unroll
            for (int j = 0; j < 4; j++) acc[t][1][j] += red[r][t][j][lane];  // full group-B sum
    }

    // ---- epilogue: kk=0 stores group A, kk=1 stores group B (C/D: col=lane&15, row=q*4+j) ----
    int gbase = (kk == 0) ? baseA : baseB;
    float dd[4];
    #pragma unroll
    for (int j = 0; j < 4; j++) {
        int row = gbase + q * 4 + j;
        dd[j] = (row < nrows) ? dinv[row] : 0.f;
    }
    if (kk == 0) {
        #pragma unroll
        for (int t = 0; t < NT; t++) {
            int col = t * 16 + m;
            if ((DOUT % 16 == 0) || (col < DOUT)) {
                float bias = bs[col] + bb[col];
                #pragma unroll
                for (int j = 0; j < 4; j++) {
                    int row = gbase + q * 4 + j;
                    if (row < nrows) H[(size_t)row * hstride + col] = f2bf((acc[t][0][j] + bias) * dd[j]);
                }
            }
        }
    } else {
        #pragma unroll
        for (int t = 0; t < NT; t++) {
            int col = t * 16 + m;
            if ((DOUT % 16 == 0) || (col < DOUT)) {
                float bias = bs[col] + bb[col];
                #pragma unroll
                for (int j = 0; j < 4; j++) {
                    int row = gbase + q * 4 + j;
                    if (row < nrows) H[(size_t)row * hstride + col] = f2bf((acc[t][1][j] + bias) * dd[j]);
                }
            }
        }
    }
}

// ---------------- aggregation: wave per node, 4 edges in flight ----------------
// H is pre-scaled by dinv[src]. out = dinv[wid]*(H[wid] + sum_nbr H[s]) + bg.

__global__ __launch_bounds__(256) void agg128_kernel(
    const ushortT* __restrict__ H, ushortT* __restrict__ OUT,
    const float* __restrict__ bg, const int* __restrict__ rowptr,
    const int* __restrict__ colv, const float* __restrict__ dinv,
    float2* __restrict__ STout, int n) {
    int wid = (blockIdx.x * 256 + threadIdx.x) >> 6;
    int lane = threadIdx.x & 63;
    if (wid >= n) return;
    int g = lane >> 4, t = lane & 15;
    float di = dinv[wid];
    float a[8] = {0.f, 0.f, 0.f, 0.f, 0.f, 0.f, 0.f, 0.f};
    if (g == 0) unpack_add(*(const uint4*)(H + (size_t)wid * 128 + t * 8), a);  // self
    int e0 = rowptr[wid], e1 = rowptr[wid + 1];
    for (int e = e0 + g; e < e1; e += 4) {
        int s = colv[e];
        unpack_add(*(const uint4*)(H + (size_t)s * 128 + t * 8), a);
    }
    #pragma unroll
    for (int j = 0; j < 8; j++) {
        a[j] += __shfl_xor(a[j], 16);
        a[j] += __shfl_xor(a[j], 32);
    }
    if (g == 0) {
        float4 b0 = *(const float4*)(bg + t * 8);
        float4 b1 = *(const float4*)(bg + t * 8 + 4);
        float bgs[8] = {b0.x, b0.y, b0.z, b0.w, b1.x, b1.y, b1.z, b1.w};
        unsigned rb[8];
        float s = 0.f, ss = 0.f;
        #pragma unroll
        for (int j = 0; j < 8; j++) {
            float o = di * a[j] + bgs[j];
            rb[j] = f2bf(o);
            float back = bf2f((unsigned short)rb[j]);
            s += back; ss += back * back;
        }
        uint4 pk;
        pk.x = rb[0] | (rb[1] << 16);
        pk.y = rb[2] | (rb[3] << 16);
        pk.z = rb[4] | (rb[5] << 16);
        pk.w = rb[6] | (rb[7] << 16);
        *(uint4*)(OUT + (size_t)wid * 128 + t * 8) = pk;
        #pragma unroll
        for (int d = 1; d < 16; d <<= 1) { s += __shfl_xor(s, d); ss += __shfl_xor(ss, d); }
        if (t == 0) STout[wid] = make_float2(s, ss);
    }
}

// H stride 64 (cols 47..63 junk, never written out). 8 edges in flight.
__global__ __launch_bounds__(256) void agg47_kernel(
    const ushortT* __restrict__ H, float* __restrict__ OUT,
    const float* __restrict__ bg, const int* __restrict__ rowptr,
    const int* __restrict__ colv, const float* __restrict__ dinv, int n) {
    int wid = (blockIdx.x * 256 + threadIdx.x) >> 6;
    int lane = threadIdx.x & 63;
    if (wid >= n) return;
    int g = lane >> 3, t = lane & 7;
    float di = dinv[wid];
    float a[8] = {0.f, 0.f, 0.f, 0.f, 0.f, 0.f, 0.f, 0.f};
    if (g == 0) unpack_add(*(const uint4*)(H + (size_t)wid * 64 + t * 8), a);  // self
    int e0 = rowptr[wid], e1 = rowptr[wid + 1];
    for (int e = e0 + g; e < e1; e += 8) {
        int s = colv[e];
        unpack_add(*(const uint4*)(H + (size_t)s * 64 + t * 8), a);
    }
    #pragma unroll
    for (int j = 0; j < 8; j++) {
        a[j] += __shfl_xor(a[j], 8);
        a[j] += __shfl_xor(a[j], 16);
        a[j] += __shfl_xor(a[j], 32);
    }
    if (g == 0) {
        #pragma unroll
        for (int j = 0; j < 8; j++) {
            int c = t * 8 + j;
            if (c < 47) OUT[(size_t)wid * 47 + c] = di * a[j] + bg[c];
        }
    }
}

// ---------------- launcher ----------------

extern "C" void kernel_launch(void* const* d_in, const int* in_sizes, int n_in,
                              void* d_out, int out_size, void* d_ws, size_t ws_size,
                              hipStream_t stream) {
    const float* x = (const float*)d_in[0];
    const int* ei = (const int*)d_in[1];
    const float* lng0 = (const float*)d_in[2];
    const float* lnb0 = (const float*)d_in[3];
    const float* Ws0 = (const float*)d_in[4];
    const float* bs0 = (const float*)d_in[5];
    const float* Wb0 = (const float*)d_in[6];
    const float* bb0 = (const float*)d_in[7];
    const float* bg0 = (const float*)d_in[8];
    const float* lng1 = (const float*)d_in[9];
    const float* lnb1 = (const float*)d_in[10];
    const float* Ws1 = (const float*)d_in[11];
    const float* bs1 = (const float*)d_in[12];
    const float* Wb1 = (const float*)d_in[13];
    const float* bb1 = (const float*)d_in[14];
    const float* bg1 = (const float*)d_in[15];
    const float* lng2 = (const float*)d_in[16];
    const float* lnb2 = (const float*)d_in[17];
    const float* Ws2 = (const float*)d_in[18];
    const float* bs2 = (const float*)d_in[19];
    const float* Wb2 = (const float*)d_in[20];
    const float* bb2 = (const float*)d_in[21];
    const float* bg2 = (const float*)d_in[22];

    const int N = in_sizes[0] / 128;
    const int E = in_sizes[1] / 2;
    const int NB = (N + 255) >> 8;  // coarse buckets of 256 nodes (requires N < 2^24)

    char* wsp = (char*)d_ws;
    size_t off = 0;
    auto alloc = [&](size_t bytes) {
        off = (off + 255) & ~(size_t)255;
        void* p = wsp + off;
        off += bytes;
        return p;
    };
    int* ghist = (int*)alloc(512 * 4);
    int* bbase = (int*)alloc(513 * 4);
    int* gcur = (int*)alloc(512 * 4);
    int* rowptr = (int*)alloc((size_t)(N + 1) * 4);
    int* colv = (int*)alloc((size_t)E * 4);
    float* dinvv = (float*)alloc((size_t)N * 4);
    ushortT* hbuf = (ushortT*)alloc((size_t)N * 128 * 2);
    ushortT* a1 = (ushortT*)alloc((size_t)N * 128 * 2);
    ushortT* a2 = (ushortT*)alloc((size_t)N * 128 * 2);
    float2* stx = (float2*)alloc((size_t)N * 8);
    float2* st1 = (float2*)alloc((size_t)N * 8);
    float2* st2 = (float2*)alloc((size_t)N * 8);
    ushortT* Wc0 = (ushortT*)alloc((size_t)128 * 640 * 2);
    ushortT* Wc1 = (ushortT*)alloc((size_t)128 * 640 * 2);
    ushortT* Wc2 = (ushortT*)alloc((size_t)47 * 1920 * 2);
    size_t off_base = off;
    ushortT* xb = (ushortT*)alloc((size_t)N * 128 * 2);  // bf16 mirror of x
    bool fits = (off <= ws_size);
    if (!fits) off = off_base;
    (void)n_in; (void)out_size;

    // pairs staging aliases hbuf: pairs is dead before the first fkan writes hbuf.
    unsigned* pairs = (unsigned*)hbuf;

    const int* srcp = ei;
    const int* dstp = ei + E;

    int gF = (N + 63) / 64;
    int gW = (N + 3) / 4;
    int gScat = (E + SCAT_CH - 1) / SCAT_CH;

    build_wc<<<(128 * 640 + 255) / 256, 256, 0, stream>>>(Ws0, Wb0, Wc0, 128, 128);
    build_wc<<<(128 * 640 + 255) / 256, 256, 0, stream>>>(Ws1, Wb1, Wc1, 128, 128);
    build_wc<<<(47 * 1920 + 255) / 256, 256, 0, stream>>>(Ws2, Wb2, Wc2, 47, 384);

    // CSR build: coarse hist -> scan -> coarse scatter (packed pairs) -> fine per-bucket CSR
    zero_ints<<<2, 256, 0, stream>>>(ghist, 512);
    coarse_hist<<<NB, 256, 0, stream>>>(dstp, ghist, E, NB);
    bucket_scan<<<1, 64, 0, stream>>>(ghist, bbase, gcur, NB);
    coarse_scatter<<<gScat, 256, 0, stream>>>(srcp, dstp, gcur, pairs, E, NB);
    fine_csr<<<NB, 256, 0, stream>>>(pairs, bbase, rowptr, colv, dinvv, N, E);

    stats_f32<<<gW, 256, 0, stream>>>(x, stx, fits ? xb : nullptr, N);

    // layer 1
    if (fits)
        fkan_kernel<1, 128, 0><<<gF, 256, 0, stream>>>(xb, 128, xb, 128, xb, 128, stx, stx, stx,
                                                       lng0, lnb0, Wc0, bs0, bb0, dinvv, hbuf, 128, N);
    else
        fkan_kernel<1, 128, 1><<<gF, 256, 0, stream>>>(x, 128, x, 128, x, 128, stx, stx, stx,
                                                       lng0, lnb0, Wc0, bs0, bb0, dinvv, hbuf, 128, N);
    agg128_kernel<<<gW, 256, 0, stream>>>(hbuf, a1, bg0, rowptr, colv, dinvv, st1, N);

    // layer 2
    fkan_kernel<1, 128, 0><<<gF, 256, 0, stream>>>(a1, 128, a1, 128, a1, 128, st1, st1, st1,
                                                   lng1, lnb1, Wc1, bs1, bb1, dinvv, hbuf, 128, N);
    agg128_kernel<<<gW, 256, 0, stream>>>(hbuf, a2, bg1, rowptr, colv, dinvv, st2, N);

    // layer 3 (hbuf stride 64)
    if (fits)
        fkan_kernel<3, 47, 0><<<gF, 256, 0, stream>>>(xb, 128, a1, 128, a2, 128, stx, st1, st2,
                                                      lng2, lnb2, Wc2, bs2, bb2, dinvv, hbuf, 64, N);
    else
        fkan_kernel<3, 47, 1><<<gF, 256, 0, stream>>>(x, 128, a1, 128, a2, 128, stx, st1, st2,
                                                      lng2, lnb2, Wc2, bs2, bb2, dinvv, hbuf, 64, N);
    agg47_kernel<<<gW, 256, 0, stream>>>(hbuf, (float*)d_out, bg2, rowptr, colv, dinvv, N);
}

// Round 5
// 729.526 us; speedup vs baseline: 1.2069x; 1.0000x over previous
//
#include <hip/hip_runtime.h>

typedef unsigned short ushortT;
typedef _Float16 f16x8 __attribute__((ext_vector_type(8)));
typedef __attribute__((ext_vector_type(4))) float float4v;
typedef __attribute__((ext_vector_type(4))) unsigned int uint4v;

__device__ __forceinline__ unsigned short f2h(float f) {  // RTNE f32->f16 (v_cvt_f16_f32)
    _Float16 h = (_Float16)f;
    return __builtin_bit_cast(unsigned short, h);
}
__device__ __forceinline__ float h2f(unsigned short b) {  // v_cvt_f32_f16
    return (float)__builtin_bit_cast(_Float16, b);
}
// packed f32x2 -> f16x2, RTZ (v_cvt_pkrtz_f16_f32, 1 inst). RTZ in f16 domain = 2^-11
// relative truncation, ~8x below bf16 RTNE rounding -> no round-2-style bias failure.
__device__ __forceinline__ unsigned pkrtz(float lo, float hi) {
    auto h = __builtin_amdgcn_cvt_pkrtz(lo, hi);
    return __builtin_bit_cast(unsigned, h);
}
__device__ __forceinline__ f16x8 pack8h(const float e[8]) {
    uint4v u;
    u[0] = pkrtz(e[0], e[1]);
    u[1] = pkrtz(e[2], e[3]);
    u[2] = pkrtz(e[4], e[5]);
    u[3] = pkrtz(e[6], e[7]);
    return __builtin_bit_cast(f16x8, u);
}
__device__ __forceinline__ void unpack_add(uint4 v, float a[8]) {  // f16 pairs
    unsigned uu[4] = {v.x, v.y, v.z, v.w};
    #pragma unroll
    for (int j = 0; j < 8; j++) a[j] += h2f((unsigned short)(uu[j >> 1] >> ((j & 1) * 16)));
}

// 8-element row load; f32 flag folds at compile time (16-bit path = f16 storage)
__device__ __forceinline__ void loadc8(bool f32, const void* p, size_t off, float o[8]) {
    if (f32) {
        const float* q = (const float*)p + off;
        float4 a = *(const float4*)q;
        float4 b = *(const float4*)(q + 4);
        o[0] = a.x; o[1] = a.y; o[2] = a.z; o[3] = a.w;
        o[4] = b.x; o[5] = b.y; o[6] = b.z; o[7] = b.w;
    } else {
        uint4 v = *(const uint4*)((const ushortT*)p + off);
        unsigned uu[4] = {v.x, v.y, v.z, v.w};
        #pragma unroll
        for (int j = 0; j < 8; j++) o[j] = h2f((unsigned short)(uu[j >> 1] >> ((j & 1) * 16)));
    }
}

// ---------------- combined weight build: Wc[n][seg*512+g*128+dl | 4*DIN+d] (f16) ----------------
__global__ __launch_bounds__(256) void build_wc(const float* __restrict__ Ws, const float* __restrict__ Wb,
                                                ushortT* __restrict__ Wc, int dout, int din) {
    int idx = blockIdx.x * 256 + threadIdx.x;
    int kw = 5 * din;
    if (idx >= dout * kw) return;
    int n = idx / kw, c = idx % kw;
    float v;
    if (c < 4 * din) {
        int seg = c >> 9;
        int rem = c & 511;
        int g = rem >> 7;
        int dl = rem & 127;
        v = Ws[(size_t)n * 4 * din + 4 * (seg * 128 + dl) + g];
    } else {
        v = Wb[(size_t)n * din + (c - 4 * din)];
    }
    Wc[idx] = f2h(v);
}

// ---------------- per-row LN stats for f32 x (+ optional f16 mirror) ----------------

__global__ __launch_bounds__(256) void stats_f32(const float* __restrict__ X, float2* __restrict__ ST,
                                                 ushortT* __restrict__ xb, int n) {
    int wid = (blockIdx.x * 256 + threadIdx.x) >> 6;
    int lane = threadIdx.x & 63;
    if (wid >= n) return;
    float2 v = *(const float2*)(X + (size_t)wid * 128 + lane * 2);
    if (xb) {
        *(unsigned*)(xb + (size_t)wid * 128 + lane * 2) = pkrtz(v.x, v.y);
    }
    float s = v.x + v.y, ss = v.x * v.x + v.y * v.y;
    #pragma unroll
    for (int d = 1; d < 64; d <<= 1) { s += __shfl_xor(s, d); ss += __shfl_xor(ss, d); }
    if (lane == 0) ST[wid] = make_float2(s, ss);
}

// ---------------- CSR build: two-level counting sort ----------------
// Pack: src (bits 0..23, N < 2^24) | (dst & 255) << 24. Coarse bucket = dst >> 8.

__global__ __launch_bounds__(256) void zero_ints(int* p, int n) {
    int i = blockIdx.x * 256 + threadIdx.x;
    if (i < n) p[i] = 0;
}

__device__ __forceinline__ int wave_incl_scan(int v, int lane) {
    #pragma unroll
    for (int d = 1; d < 64; d <<= 1) {
        int o = __shfl_up(v, d);
        if (lane >= d) v += o;
    }
    return v;
}

// coarse histogram of dst>>8 (LDS-staged; ~nb global atomics per block)
__global__ __launch_bounds__(256) void coarse_hist(const int* __restrict__ dst, int* __restrict__ ghist,
                                                   int E, int nb) {
    __shared__ int h[512];
    for (int i = threadIdx.x; i < 512; i += 256) h[i] = 0;
    __syncthreads();
    int stride = gridDim.x * 256;
    for (int e = blockIdx.x * 256 + threadIdx.x; e < E; e += stride) {
        atomicAdd(&h[dst[e] >> 8], 1);
    }
    __syncthreads();
    for (int i = threadIdx.x; i < nb; i += 256) {
        int c = h[i];
        if (c) atomicAdd(&ghist[i], c);
    }
}

// exclusive scan of nb (<=512) bucket counts; writes base[0..nb] and a working copy gcur
__global__ __launch_bounds__(64) void bucket_scan(const int* __restrict__ ghist, int* __restrict__ base,
                                                  int* __restrict__ gcur, int nb) {
    int lane = threadIdx.x;
    int carry = 0;
    for (int b0 = 0; b0 < nb; b0 += 64) {
        int i = b0 + lane;
        int v = (i < nb) ? ghist[i] : 0;
        int incl = wave_incl_scan(v, lane);
        if (i < nb) { int ex = carry + incl - v; base[i] = ex; gcur[i] = ex; }
        carry += __shfl(incl, 63);
    }
    if (lane == 0) base[nb] = carry;
}

// bin edges into coarse buckets. Per block: LDS hist of its chunk, ONE global atomic per
// (block,bucket) to reserve a contiguous run, then LDS-cursor scatter -> runs of ~10 words.
#define SCAT_CH 4096
__global__ __launch_bounds__(256) void coarse_scatter(const int* __restrict__ src, const int* __restrict__ dst,
                                                      int* __restrict__ gcur, unsigned* __restrict__ pairs,
                                                      int E, int nb) {
    __shared__ int cur[512];
    for (int i = threadIdx.x; i < 512; i += 256) cur[i] = 0;
    __syncthreads();
    int e0 = blockIdx.x * SCAT_CH;
    int e1 = min(e0 + SCAT_CH, E);
    for (int e = e0 + threadIdx.x; e < e1; e += 256) atomicAdd(&cur[dst[e] >> 8], 1);
    __syncthreads();
    for (int i = threadIdx.x; i < nb; i += 256) {
        int c = cur[i];
        cur[i] = c ? atomicAdd(&gcur[i], c) : 0;
    }
    __syncthreads();
    for (int e = e0 + threadIdx.x; e < e1; e += 256) {
        int d = dst[e];
        int r = atomicAdd(&cur[d >> 8], 1);
        pairs[r] = (unsigned)src[e] | ((unsigned)(d & 255) << 24);
    }
}

// one block per coarse bucket: fine 256-bin hist -> rowptr + dinv, then scatter colv
// entirely inside the bucket's contiguous output window (full line utilization).
__global__ __launch_bounds__(256) void fine_csr(const unsigned* __restrict__ pairs, const int* __restrict__ base,
                                                int* __restrict__ rowptr, int* __restrict__ colv,
                                                float* __restrict__ dinv, int n, int E) {
    __shared__ int h[256];
    __shared__ int cur[256];
    __shared__ int wt[4];
    int b = blockIdx.x, tid = threadIdx.x;
    int e0 = base[b], e1 = base[b + 1];
    h[tid] = 0;
    __syncthreads();
    for (int e = e0 + tid; e < e1; e += 256) atomicAdd(&h[pairs[e] >> 24], 1);
    __syncthreads();
    int v = h[tid];
    int lane = tid & 63, w = tid >> 6;
    int incl = wave_incl_scan(v, lane);
    if (lane == 63) wt[w] = incl;
    __syncthreads();
    int woff = 0;
    for (int i = 0; i < w; i++) woff += wt[i];
    int excl = woff + incl - v;
    int node = b * 256 + tid;
    if (node < n) {
        rowptr[node] = e0 + excl;
        dinv[node] = rsqrtf((float)(v + 1));  // +1 self loop
        if (node == n - 1) rowptr[n] = E;
    }
    cur[tid] = e0 + excl;
    __syncthreads();
    for (int e = e0 + tid; e < e1; e += 256) {
        unsigned p = pairs[e];
        int r = atomicAdd(&cur[p >> 24], 1);
        colv[r] = (int)(p & 0x00FFFFFFu);
    }
}

// ---------------- fused FastKAN transform (f16 MFMA pipeline) ----------------
// Round-4 structure: block = 64 rows, 4 waves = 2 row-panels x 2 K-halves; each wave keeps
// 2 row-groups sharing each Wc B-fragment (round-3 lesson) + K-split occupancy (round-4).
// Round-5: bf16 -> f16. v_cvt_pkrtz_f16_f32 packs 2 activations in 1 inst (vs ~9 for f2bf
// pair); f16 RTZ bias (2^-11 rel) is ~8x below bf16 RTNE step -> no round-2 bias failure.
// mfma_f32_16x16x32_f16: identical rate + C/D layout as bf16.
template <int NSEG, int DOUT, int F32MASK>
__global__ __launch_bounds__(256) void fkan_kernel(
    const void* __restrict__ X0, int s0,
    const void* __restrict__ X1, int s1,
    const void* __restrict__ X2, int s2,
    const float2* __restrict__ ST0, const float2* __restrict__ ST1, const float2* __restrict__ ST2,
    const float* __restrict__ lng, const float* __restrict__ lnb,
    const ushortT* __restrict__ Wc,
    const float* __restrict__ bs, const float* __restrict__ bb,
    const float* __restrict__ dinv,
    ushortT* __restrict__ H, int hstride, int nrows) {
    constexpr int DIN = NSEG * 128;
    constexpr int KW = 5 * DIN;
    constexpr int NT = (DOUT + 15) / 16;
    __shared__ float red[2][NT][4][64];  // [panel][tile][reg][lane]
    int tid = threadIdx.x;
    int w = tid >> 6, lane = tid & 63;
    int m = lane & 15, q = lane >> 4;
    int r = w & 1;    // row panel
    int kk = w >> 1;  // K half
    int baseA = blockIdx.x * 64 + r * 16;
    int baseB = baseA + 32;
    int rA = min(baseA + m, nrows - 1);
    int rB = min(baseB + m, nrows - 1);

    float muA, scA, muB, scB;
    {
        float2 st = ST0[rA]; float sum = st.x, ssq = st.y;
        if (NSEG == 3) { float2 t1 = ST1[rA]; sum += t1.x; ssq += t1.y; float2 t2 = ST2[rA]; sum += t2.x; ssq += t2.y; }
        muA = sum * (1.0f / DIN);
        float var = ssq * (1.0f / DIN) - muA * muA;
        scA = rsqrtf(fmaxf(var, 0.0f) + 1e-5f);
    }
    {
        float2 st = ST0[rB]; float sum = st.x, ssq = st.y;
        if (NSEG == 3) { float2 t1 = ST1[rB]; sum += t1.x; ssq += t1.y; float2 t2 = ST2[rB]; sum += t2.x; ssq += t2.y; }
        muB = sum * (1.0f / DIN);
        float var = ssq * (1.0f / DIN) - muB * muB;
        scB = rsqrtf(fmaxf(var, 0.0f) + 1e-5f);
    }

    float4v acc[NT][2];
    #pragma unroll
    for (int t = 0; t < NT; t++) {
        acc[t][0] = (float4v){0.f, 0.f, 0.f, 0.f};
        acc[t][1] = (float4v){0.f, 0.f, 0.f, 0.f};
    }

    const float G[4] = {-2.f, -2.f / 3.f, 2.f / 3.f, 2.f};

    // ---- RBF region (this wave's K-half only) ----
    #pragma unroll
    for (int seg = 0; seg < NSEG; seg++) {
        const void* Xp = (seg == 0) ? X0 : (seg == 1) ? X1 : X2;
        int str = (seg == 0) ? s0 : (seg == 1) ? s1 : s2;
        bool f32 = ((F32MASK >> seg) & 1) != 0;
        #pragma unroll
        for (int i = 0; i < 4; i++) {
            if (((seg * 4 + i) & 1) != kk) continue;
            int d0 = i * 32 + q * 8;
            float xa[8], xb8[8];
            loadc8(f32, Xp, (size_t)rA * str + d0, xa);
            loadc8(f32, Xp, (size_t)rB * str + d0, xb8);
            float4 gv0 = *(const float4*)(lng + seg * 128 + d0);
            float4 gv1 = *(const float4*)(lng + seg * 128 + d0 + 4);
            float4 bv0 = *(const float4*)(lnb + seg * 128 + d0);
            float4 bv1 = *(const float4*)(lnb + seg * 128 + d0 + 4);
            float gvs[8] = {gv0.x, gv0.y, gv0.z, gv0.w, gv1.x, gv1.y, gv1.z, gv1.w};
            float bvs[8] = {bv0.x, bv0.y, bv0.z, bv0.w, bv1.x, bv1.y, bv1.z, bv1.w};
            float za[8], zb[8];
            #pragma unroll
            for (int j = 0; j < 8; j++) {
                za[j] = (xa[j] - muA) * scA * gvs[j] + bvs[j];
                zb[j] = (xb8[j] - muB) * scB * gvs[j] + bvs[j];
            }
            #pragma unroll
            for (int g = 0; g < 4; g++) {
                float ea[8], eb[8];
                #pragma unroll
                for (int j = 0; j < 8; j++) {
                    float da = (za[j] - G[g]) * 0.75f;
                    ea[j] = __expf(-da * da);
                    float db = (zb[j] - G[g]) * 0.75f;
                    eb[j] = __expf(-db * db);
                }
                f16x8 afa = pack8h(ea);
                f16x8 afb = pack8h(eb);
                int kbase = seg * 512 + g * 128 + i * 32;
                #pragma unroll
                for (int t = 0; t < NT; t++) {
                    int n = t * 16 + m;
                    f16x8 bfr = (f16x8)(_Float16)0;
                    if ((DOUT % 16 == 0) || (n < DOUT))
                        bfr = *(const f16x8*)(Wc + (size_t)n * KW + kbase + q * 8);
                    acc[t][0] = __builtin_amdgcn_mfma_f32_16x16x32_f16(afa, bfr, acc[t][0], 0, 0, 0);
                    acc[t][1] = __builtin_amdgcn_mfma_f32_16x16x32_f16(afb, bfr, acc[t][1], 0, 0, 0);
                }
            }
        }
    }

    // ---- SiLU region (this wave's K-half only) ----
    #pragma unroll
    for (int seg = 0; seg < NSEG; seg++) {
        const void* Xp = (seg == 0) ? X0 : (seg == 1) ? X1 : X2;
        int str = (seg == 0) ? s0 : (seg == 1) ? s1 : s2;
        bool f32 = ((F32MASK >> seg) & 1) != 0;
        #pragma unroll
        for (int i = 0; i < 4; i++) {
            if (((seg * 4 + i) & 1) != kk) continue;
            int c = i * 32 + q * 8;
            float xa[8], xb8[8];
            loadc8(f32, Xp, (size_t)rA * str + c, xa);
            loadc8(f32, Xp, (size_t)rB * str + c, xb8);
            float ea[8], eb[8];
            #pragma unroll
            for (int j = 0; j < 8; j++) {
                float sa = 1.0f / (1.0f + __expf(-xa[j]));
                ea[j] = xa[j] * sa;
                float sb = 1.0f / (1.0f + __expf(-xb8[j]));
                eb[j] = xb8[j] * sb;
            }
            f16x8 afa = pack8h(ea);
            f16x8 afb = pack8h(eb);
            int kbase = 4 * DIN + seg * 128 + i * 32;
            #pragma unroll
            for (int t = 0; t < NT; t++) {
                int n = t * 16 + m;
                f16x8 bfr = (f16x8)(_Float16)0;
                if ((DOUT % 16 == 0) || (n < DOUT))
                    bfr = *(const f16x8*)(Wc + (size_t)n * KW + kbase + q * 8);
                acc[t][0] = __builtin_amdgcn_mfma_f32_16x16x32_f16(afa, bfr, acc[t][0], 0, 0, 0);
                acc[t][1] = __builtin_amdgcn_mfma_f32_16x16x32_f16(afb, bfr, acc[t][1], 0, 0, 0);
            }
        }
    }

    // ---- cross-wave K-half reduction (2 barriers, self-ordered LDS reuse) ----
    if (kk == 1) {
        #pragma unroll
        for (int t = 0; t < NT; t++)
            #pragma unroll
            for (int j = 0; j < 4; j++) red[r][t][j][lane] = acc[t][0][j];
    }
    __syncthreads();
    if (kk == 0) {
        #pragma unroll
        for (int t = 0; t < NT; t++)
            #pragma unroll
            for (int j = 0; j < 4; j++) {
                acc[t][0][j] += red[r][t][j][lane];  // full group-A sum
                red[r][t][j][lane] = acc[t][1][j];   // hand B partial to the k=1 wave
            }
    }
    __syncthreads();
    if (kk == 1) {
        #pragma unroll
        for (int t = 0; t < NT; t++)
            #pragma unroll
            for (int j = 0; j < 4; j++) acc[t][1][j] += red[r][t][j][lane];  // full group-B sum
    }

    // ---- epilogue: kk=0 stores group A, kk=1 stores group B (C/D: col=lane&15, row=q*4+j) ----
    int gbase = (kk == 0) ? baseA : baseB;
    float dd[4];
    #pragma unroll
    for (int j = 0; j < 4; j++) {
        int row = gbase + q * 4 + j;
        dd[j] = (row < nrows) ? dinv[row] : 0.f;
    }
    if (kk == 0) {
        #pragma unroll
        for (int t = 0; t < NT; t++) {
            int col = t * 16 + m;
            if ((DOUT % 16 == 0) || (col < DOUT)) {
                float bias = bs[col] + bb[col];
                #pragma unroll
                for (int j = 0; j < 4; j++) {
                    int row = gbase + q * 4 + j;
                    if (row < nrows) H[(size_t)row * hstride + col] = f2h((acc[t][0][j] + bias) * dd[j]);
                }
            }
        }
    } else {
        #pragma unroll
        for (int t = 0; t < NT; t++) {
            int col = t * 16 + m;
            if ((DOUT % 16 == 0) || (col < DOUT)) {
                float bias = bs[col] + bb[col];
                #pragma unroll
                for (int j = 0; j < 4; j++) {
                    int row = gbase + q * 4 + j;
                    if (row < nrows) H[(size_t)row * hstride + col] = f2h((acc[t][1][j] + bias) * dd[j]);
                }
            }
        }
    }
}

// ---------------- aggregation: wave per node, 4 edges in flight ----------------
// H (f16) is pre-scaled by dinv[src]. out = dinv[wid]*(H[wid] + sum_nbr H[s]) + bg.

__global__ __launch_bounds__(256) void agg128_kernel(
    const ushortT* __restrict__ H, ushortT* __restrict__ OUT,
    const float* __restrict__ bg, const int* __restrict__ rowptr,
    const int* __restrict__ colv, const float* __restrict__ dinv,
    float2* __restrict__ STout, int n) {
    int wid = (blockIdx.x * 256 + threadIdx.x) >> 6;
    int lane = threadIdx.x & 63;
    if (wid >= n) return;
    int g = lane >> 4, t = lane & 15;
    float di = dinv[wid];
    float a[8] = {0.f, 0.f, 0.f, 0.f, 0.f, 0.f, 0.f, 0.f};
    if (g == 0) unpack_add(*(const uint4*)(H + (size_t)wid * 128 + t * 8), a);  // self
    int e0 = rowptr[wid], e1 = rowptr[wid + 1];
    for (int e = e0 + g; e < e1; e += 4) {
        int s = colv[e];
        unpack_add(*(const uint4*)(H + (size_t)s * 128 + t * 8), a);
    }
    #pragma unroll
    for (int j = 0; j < 8; j++) {
        a[j] += __shfl_xor(a[j], 16);
        a[j] += __shfl_xor(a[j], 32);
    }
    if (g == 0) {
        float4 b0 = *(const float4*)(bg + t * 8);
        float4 b1 = *(const float4*)(bg + t * 8 + 4);
        float bgs[8] = {b0.x, b0.y, b0.z, b0.w, b1.x, b1.y, b1.z, b1.w};
        unsigned rb[8];
        float s = 0.f, ss = 0.f;
        #pragma unroll
        for (int j = 0; j < 8; j++) {
            float o = di * a[j] + bgs[j];
            rb[j] = f2h(o);                       // RTNE; stored value
            float back = h2f((unsigned short)rb[j]);
            s += back; ss += back * back;         // stats of STORED values (LN consistency)
        }
        uint4 pk;
        pk.x = rb[0] | (rb[1] << 16);
        pk.y = rb[2] | (rb[3] << 16);
        pk.z = rb[4] | (rb[5] << 16);
        pk.w = rb[6] | (rb[7] << 16);
        *(uint4*)(OUT + (size_t)wid * 128 + t * 8) = pk;
        #pragma unroll
        for (int d = 1; d < 16; d <<= 1) { s += __shfl_xor(s, d); ss += __shfl_xor(ss, d); }
        if (t == 0) STout[wid] = make_float2(s, ss);
    }
}

// H stride 64 (cols 47..63 junk, never written out). 8 edges in flight.
__global__ __launch_bounds__(256) void agg47_kernel(
    const ushortT* __restrict__ H, float* __restrict__ OUT,
    const float* __restrict__ bg, const int* __restrict__ rowptr,
    const int* __restrict__ colv, const float* __restrict__ dinv, int n) {
    int wid = (blockIdx.x * 256 + threadIdx.x) >> 6;
    int lane = threadIdx.x & 63;
    if (wid >= n) return;
    int g = lane >> 3, t = lane & 7;
    float di = dinv[wid];
    float a[8] = {0.f, 0.f, 0.f, 0.f, 0.f, 0.f, 0.f, 0.f};
    if (g == 0) unpack_add(*(const uint4*)(H + (size_t)wid * 64 + t * 8), a);  // self
    int e0 = rowptr[wid], e1 = rowptr[wid + 1];
    for (int e = e0 + g; e < e1; e += 8) {
        int s = colv[e];
        unpack_add(*(const uint4*)(H + (size_t)s * 64 + t * 8), a);
    }
    #pragma unroll
    for (int j = 0; j < 8; j++) {
        a[j] += __shfl_xor(a[j], 8);
        a[j] += __shfl_xor(a[j], 16);
        a[j] += __shfl_xor(a[j], 32);
    }
    if (g == 0) {
        #pragma unroll
        for (int j = 0; j < 8; j++) {
            int c = t * 8 + j;
            if (c < 47) OUT[(size_t)wid * 47 + c] = di * a[j] + bg[c];
        }
    }
}

// ---------------- launcher ----------------

extern "C" void kernel_launch(void* const* d_in, const int* in_sizes, int n_in,
                              void* d_out, int out_size, void* d_ws, size_t ws_size,
                              hipStream_t stream) {
    const float* x = (const float*)d_in[0];
    const int* ei = (const int*)d_in[1];
    const float* lng0 = (const float*)d_in[2];
    const float* lnb0 = (const float*)d_in[3];
    const float* Ws0 = (const float*)d_in[4];
    const float* bs0 = (const float*)d_in[5];
    const float* Wb0 = (const float*)d_in[6];
    const float* bb0 = (const float*)d_in[7];
    const float* bg0 = (const float*)d_in[8];
    const float* lng1 = (const float*)d_in[9];
    const float* lnb1 = (const float*)d_in[10];
    const float* Ws1 = (const float*)d_in[11];
    const float* bs1 = (const float*)d_in[12];
    const float* Wb1 = (const float*)d_in[13];
    const float* bb1 = (const float*)d_in[14];
    const float* bg1 = (const float*)d_in[15];
    const float* lng2 = (const float*)d_in[16];
    const float* lnb2 = (const float*)d_in[17];
    const float* Ws2 = (const float*)d_in[18];
    const float* bs2 = (const float*)d_in[19];
    const float* Wb2 = (const float*)d_in[20];
    const float* bb2 = (const float*)d_in[21];
    const float* bg2 = (const float*)d_in[22];

    const int N = in_sizes[0] / 128;
    const int E = in_sizes[1] / 2;
    const int NB = (N + 255) >> 8;  // coarse buckets of 256 nodes (requires N < 2^24)

    char* wsp = (char*)d_ws;
    size_t off = 0;
    auto alloc = [&](size_t bytes) {
        off = (off + 255) & ~(size_t)255;
        void* p = wsp + off;
        off += bytes;
        return p;
    };
    int* ghist = (int*)alloc(512 * 4);
    int* bbase = (int*)alloc(513 * 4);
    int* gcur = (int*)alloc(512 * 4);
    int* rowptr = (int*)alloc((size_t)(N + 1) * 4);
    int* colv = (int*)alloc((size_t)E * 4);
    float* dinvv = (float*)alloc((size_t)N * 4);
    ushortT* hbuf = (ushortT*)alloc((size_t)N * 128 * 2);
    ushortT* a1 = (ushortT*)alloc((size_t)N * 128 * 2);
    ushortT* a2 = (ushortT*)alloc((size_t)N * 128 * 2);
    float2* stx = (float2*)alloc((size_t)N * 8);
    float2* st1 = (float2*)alloc((size_t)N * 8);
    float2* st2 = (float2*)alloc((size_t)N * 8);
    ushortT* Wc0 = (ushortT*)alloc((size_t)128 * 640 * 2);
    ushortT* Wc1 = (ushortT*)alloc((size_t)128 * 640 * 2);
    ushortT* Wc2 = (ushortT*)alloc((size_t)47 * 1920 * 2);
    size_t off_base = off;
    ushortT* xb = (ushortT*)alloc((size_t)N * 128 * 2);  // f16 mirror of x
    bool fits = (off <= ws_size);
    if (!fits) off = off_base;
    (void)n_in; (void)out_size;

    // pairs staging aliases hbuf: pairs is dead before the first fkan writes hbuf.
    unsigned* pairs = (unsigned*)hbuf;

    const int* srcp = ei;
    const int* dstp = ei + E;

    int gF = (N + 63) / 64;
    int gW = (N + 3) / 4;
    int gScat = (E + SCAT_CH - 1) / SCAT_CH;

    build_wc<<<(128 * 640 + 255) / 256, 256, 0, stream>>>(Ws0, Wb0, Wc0, 128, 128);
    build_wc<<<(128 * 640 + 255) / 256, 256, 0, stream>>>(Ws1, Wb1, Wc1, 128, 128);
    build_wc<<<(47 * 1920 + 255) / 256, 256, 0, stream>>>(Ws2, Wb2, Wc2, 47, 384);

    // CSR build: coarse hist -> scan -> coarse scatter (packed pairs) -> fine per-bucket CSR
    zero_ints<<<2, 256, 0, stream>>>(ghist, 512);
    coarse_hist<<<NB, 256, 0, stream>>>(dstp, ghist, E, NB);
    bucket_scan<<<1, 64, 0, stream>>>(ghist, bbase, gcur, NB);
    coarse_scatter<<<gScat, 256, 0, stream>>>(srcp, dstp, gcur, pairs, E, NB);
    fine_csr<<<NB, 256, 0, stream>>>(pairs, bbase, rowptr, colv, dinvv, N, E);

    stats_f32<<<gW, 256, 0, stream>>>(x, stx, fits ? xb : nullptr, N);

    // layer 1
    if (fits)
        fkan_kernel<1, 128, 0><<<gF, 256, 0, stream>>>(xb, 128, xb, 128, xb, 128, stx, stx, stx,
                                                       lng0, lnb0, Wc0, bs0, bb0, dinvv, hbuf, 128, N);
    else
        fkan_kernel<1, 128, 1><<<gF, 256, 0, stream>>>(x, 128, x, 128, x, 128, stx, stx, stx,
                                                       lng0, lnb0, Wc0, bs0, bb0, dinvv, hbuf, 128, N);
    agg128_kernel<<<gW, 256, 0, stream>>>(hbuf, a1, bg0, rowptr, colv, dinvv, st1, N);

    // layer 2
    fkan_kernel<1, 128, 0><<<gF, 256, 0, stream>>>(a1, 128, a1, 128, a1, 128, st1, st1, st1,
                                                   lng1, lnb1, Wc1, bs1, bb1, dinvv, hbuf, 128, N);
    agg128_kernel<<<gW, 256, 0, stream>>>(hbuf, a2, bg1, rowptr, colv, dinvv, st2, N);

    // layer 3 (hbuf stride 64)
    if (fits)
        fkan_kernel<3, 47, 0><<<gF, 256, 0, stream>>>(xb, 128, a1, 128, a2, 128, stx, st1, st2,
                                                      lng2, lnb2, Wc2, bs2, bb2, dinvv, hbuf, 64, N);
    else
        fkan_kernel<3, 47, 1><<<gF, 256, 0, stream>>>(x, 128, a1, 128, a2, 128, stx, st1, st2,
                                                      lng2, lnb2, Wc2, bs2, bb2, dinvv, hbuf, 64, N);
    agg47_kernel<<<gW, 256, 0, stream>>>(hbuf, (float*)d_out, bg2, rowptr, colv, dinvv, N);
}

// Round 6
// 720.232 us; speedup vs baseline: 1.2224x; 1.0129x over previous
//
#include <hip/hip_runtime.h>

typedef unsigned short ushortT;
typedef _Float16 f16x8 __attribute__((ext_vector_type(8)));
typedef __attribute__((ext_vector_type(4))) float float4v;
typedef __attribute__((ext_vector_type(4))) unsigned int uint4v;

__device__ __forceinline__ unsigned short f2h(float f) {  // RTNE f32->f16 (v_cvt_f16_f32)
    _Float16 h = (_Float16)f;
    return __builtin_bit_cast(unsigned short, h);
}
__device__ __forceinline__ float h2f(unsigned short b) {  // v_cvt_f32_f16
    return (float)__builtin_bit_cast(_Float16, b);
}
// packed f32x2 -> f16x2, RTZ (v_cvt_pkrtz_f16_f32, 1 inst).
__device__ __forceinline__ unsigned pkrtz(float lo, float hi) {
    auto h = __builtin_amdgcn_cvt_pkrtz(lo, hi);
    return __builtin_bit_cast(unsigned, h);
}
__device__ __forceinline__ f16x8 pack8h(const float e[8]) {
    uint4v u;
    u[0] = pkrtz(e[0], e[1]);
    u[1] = pkrtz(e[2], e[3]);
    u[2] = pkrtz(e[4], e[5]);
    u[3] = pkrtz(e[6], e[7]);
    return __builtin_bit_cast(f16x8, u);
}
__device__ __forceinline__ void unpack_add(uint4 v, float a[8]) {  // f16 pairs
    unsigned uu[4] = {v.x, v.y, v.z, v.w};
    #pragma unroll
    for (int j = 0; j < 8; j++) a[j] += h2f((unsigned short)(uu[j >> 1] >> ((j & 1) * 16)));
}

// 8-element row load; f32 flag folds at compile time (16-bit path = f16 storage)
__device__ __forceinline__ void loadc8(bool f32, const void* p, size_t off, float o[8]) {
    if (f32) {
        const float* q = (const float*)p + off;
        float4 a = *(const float4*)q;
        float4 b = *(const float4*)(q + 4);
        o[0] = a.x; o[1] = a.y; o[2] = a.z; o[3] = a.w;
        o[4] = b.x; o[5] = b.y; o[6] = b.z; o[7] = b.w;
    } else {
        uint4 v = *(const uint4*)((const ushortT*)p + off);
        unsigned uu[4] = {v.x, v.y, v.z, v.w};
        #pragma unroll
        for (int j = 0; j < 8; j++) o[j] = h2f((unsigned short)(uu[j >> 1] >> ((j & 1) * 16)));
    }
}

// ---------------- combined weight build: Wc[n][seg*512+g*128+dl | 4*DIN+d] (f16) ----------------
__global__ __launch_bounds__(256) void build_wc(const float* __restrict__ Ws, const float* __restrict__ Wb,
                                                ushortT* __restrict__ Wc, int dout, int din) {
    int idx = blockIdx.x * 256 + threadIdx.x;
    int kw = 5 * din;
    if (idx >= dout * kw) return;
    int n = idx / kw, c = idx % kw;
    float v;
    if (c < 4 * din) {
        int seg = c >> 9;
        int rem = c & 511;
        int g = rem >> 7;
        int dl = rem & 127;
        v = Ws[(size_t)n * 4 * din + 4 * (seg * 128 + dl) + g];
    } else {
        v = Wb[(size_t)n * din + (c - 4 * din)];
    }
    Wc[idx] = f2h(v);
}

// ---------------- per-row LN stats for f32 x (+ optional f16 mirror) ----------------

__global__ __launch_bounds__(256) void stats_f32(const float* __restrict__ X, float2* __restrict__ ST,
                                                 ushortT* __restrict__ xb, int n) {
    int wid = (blockIdx.x * 256 + threadIdx.x) >> 6;
    int lane = threadIdx.x & 63;
    if (wid >= n) return;
    float2 v = *(const float2*)(X + (size_t)wid * 128 + lane * 2);
    if (xb) {
        *(unsigned*)(xb + (size_t)wid * 128 + lane * 2) = pkrtz(v.x, v.y);
    }
    float s = v.x + v.y, ss = v.x * v.x + v.y * v.y;
    #pragma unroll
    for (int d = 1; d < 64; d <<= 1) { s += __shfl_xor(s, d); ss += __shfl_xor(ss, d); }
    if (lane == 0) ST[wid] = make_float2(s, ss);
}

// ---------------- CSR build: two-level counting sort ----------------
// Pack: src (bits 0..23, N < 2^24) | (dst & 255) << 24. Coarse bucket = dst >> 8.

__global__ __launch_bounds__(256) void zero_ints(int* p, int n) {
    int i = blockIdx.x * 256 + threadIdx.x;
    if (i < n) p[i] = 0;
}

__device__ __forceinline__ int wave_incl_scan(int v, int lane) {
    #pragma unroll
    for (int d = 1; d < 64; d <<= 1) {
        int o = __shfl_up(v, d);
        if (lane >= d) v += o;
    }
    return v;
}

// coarse histogram of dst>>8 (LDS-staged; ~nb global atomics per block)
__global__ __launch_bounds__(256) void coarse_hist(const int* __restrict__ dst, int* __restrict__ ghist,
                                                   int E, int nb) {
    __shared__ int h[512];
    for (int i = threadIdx.x; i < 512; i += 256) h[i] = 0;
    __syncthreads();
    int stride = gridDim.x * 256;
    for (int e = blockIdx.x * 256 + threadIdx.x; e < E; e += stride) {
        atomicAdd(&h[dst[e] >> 8], 1);
    }
    __syncthreads();
    for (int i = threadIdx.x; i < nb; i += 256) {
        int c = h[i];
        if (c) atomicAdd(&ghist[i], c);
    }
}

// exclusive scan of nb (<=512) bucket counts; writes base[0..nb] and a working copy gcur
__global__ __launch_bounds__(64) void bucket_scan(const int* __restrict__ ghist, int* __restrict__ base,
                                                  int* __restrict__ gcur, int nb) {
    int lane = threadIdx.x;
    int carry = 0;
    for (int b0 = 0; b0 < nb; b0 += 64) {
        int i = b0 + lane;
        int v = (i < nb) ? ghist[i] : 0;
        int incl = wave_incl_scan(v, lane);
        if (i < nb) { int ex = carry + incl - v; base[i] = ex; gcur[i] = ex; }
        carry += __shfl(incl, 63);
    }
    if (lane == 0) base[nb] = carry;
}

// bin edges into coarse buckets. Per block: LDS hist of its chunk, ONE global atomic per
// (block,bucket) to reserve a contiguous run, then LDS-cursor scatter -> runs of ~10 words.
#define SCAT_CH 4096
__global__ __launch_bounds__(256) void coarse_scatter(const int* __restrict__ src, const int* __restrict__ dst,
                                                      int* __restrict__ gcur, unsigned* __restrict__ pairs,
                                                      int E, int nb) {
    __shared__ int cur[512];
    for (int i = threadIdx.x; i < 512; i += 256) cur[i] = 0;
    __syncthreads();
    int e0 = blockIdx.x * SCAT_CH;
    int e1 = min(e0 + SCAT_CH, E);
    for (int e = e0 + threadIdx.x; e < e1; e += 256) atomicAdd(&cur[dst[e] >> 8], 1);
    __syncthreads();
    for (int i = threadIdx.x; i < nb; i += 256) {
        int c = cur[i];
        cur[i] = c ? atomicAdd(&gcur[i], c) : 0;
    }
    __syncthreads();
    for (int e = e0 + threadIdx.x; e < e1; e += 256) {
        int d = dst[e];
        int r = atomicAdd(&cur[d >> 8], 1);
        pairs[r] = (unsigned)src[e] | ((unsigned)(d & 255) << 24);
    }
}

// one block per coarse bucket: fine 256-bin hist -> rowptr + dinv, then scatter colv
// entirely inside the bucket's contiguous output window (full line utilization).
__global__ __launch_bounds__(256) void fine_csr(const unsigned* __restrict__ pairs, const int* __restrict__ base,
                                                int* __restrict__ rowptr, int* __restrict__ colv,
                                                float* __restrict__ dinv, int n, int E) {
    __shared__ int h[256];
    __shared__ int cur[256];
    __shared__ int wt[4];
    int b = blockIdx.x, tid = threadIdx.x;
    int e0 = base[b], e1 = base[b + 1];
    h[tid] = 0;
    __syncthreads();
    for (int e = e0 + tid; e < e1; e += 256) atomicAdd(&h[pairs[e] >> 24], 1);
    __syncthreads();
    int v = h[tid];
    int lane = tid & 63, w = tid >> 6;
    int incl = wave_incl_scan(v, lane);
    if (lane == 63) wt[w] = incl;
    __syncthreads();
    int woff = 0;
    for (int i = 0; i < w; i++) woff += wt[i];
    int excl = woff + incl - v;
    int node = b * 256 + tid;
    if (node < n) {
        rowptr[node] = e0 + excl;
        dinv[node] = rsqrtf((float)(v + 1));  // +1 self loop
        if (node == n - 1) rowptr[n] = E;
    }
    cur[tid] = e0 + excl;
    __syncthreads();
    for (int e = e0 + tid; e < e1; e += 256) {
        unsigned p = pairs[e];
        int r = atomicAdd(&cur[p >> 24], 1);
        colv[r] = (int)(p & 0x00FFFFFFu);
    }
}

// ---------------- fused FastKAN transform (f16 MFMA, single-pass RBF+SiLU) ----------------
// Block = 64 rows, 4 waves = 2 row-panels x 2 K-halves; each wave keeps 2 row-groups
// sharing each Wc B-fragment (round-3 lesson) + K-split occupancy (round-4).
// Round-6: RBF and SiLU computed from ONE X load per chunk (was two passes = 2x loads);
// each load block now feeds 5 MFMA groups (4 RBF g + 1 SiLU) -> less exposed latency.
// MFMA f32 accumulation order changes (SiLU interleaved) - f32-order noise only.
template <int NSEG, int DOUT, int F32MASK>
__global__ __launch_bounds__(256) void fkan_kernel(
    const void* __restrict__ X0, int s0,
    const void* __restrict__ X1, int s1,
    const void* __restrict__ X2, int s2,
    const float2* __restrict__ ST0, const float2* __restrict__ ST1, const float2* __restrict__ ST2,
    const float* __restrict__ lng, const float* __restrict__ lnb,
    const ushortT* __restrict__ Wc,
    const float* __restrict__ bs, const float* __restrict__ bb,
    const float* __restrict__ dinv,
    ushortT* __restrict__ H, int hstride, int nrows) {
    constexpr int DIN = NSEG * 128;
    constexpr int KW = 5 * DIN;
    constexpr int NT = (DOUT + 15) / 16;
    __shared__ float red[2][NT][4][64];  // [panel][tile][reg][lane]
    int tid = threadIdx.x;
    int w = tid >> 6, lane = tid & 63;
    int m = lane & 15, q = lane >> 4;
    int r = w & 1;    // row panel
    int kk = w >> 1;  // K half
    int baseA = blockIdx.x * 64 + r * 16;
    int baseB = baseA + 32;
    int rA = min(baseA + m, nrows - 1);
    int rB = min(baseB + m, nrows - 1);

    float muA, scA, muB, scB;
    {
        float2 st = ST0[rA]; float sum = st.x, ssq = st.y;
        if (NSEG == 3) { float2 t1 = ST1[rA]; sum += t1.x; ssq += t1.y; float2 t2 = ST2[rA]; sum += t2.x; ssq += t2.y; }
        muA = sum * (1.0f / DIN);
        float var = ssq * (1.0f / DIN) - muA * muA;
        scA = rsqrtf(fmaxf(var, 0.0f) + 1e-5f);
    }
    {
        float2 st = ST0[rB]; float sum = st.x, ssq = st.y;
        if (NSEG == 3) { float2 t1 = ST1[rB]; sum += t1.x; ssq += t1.y; float2 t2 = ST2[rB]; sum += t2.x; ssq += t2.y; }
        muB = sum * (1.0f / DIN);
        float var = ssq * (1.0f / DIN) - muB * muB;
        scB = rsqrtf(fmaxf(var, 0.0f) + 1e-5f);
    }

    float4v acc[NT][2];
    #pragma unroll
    for (int t = 0; t < NT; t++) {
        acc[t][0] = (float4v){0.f, 0.f, 0.f, 0.f};
        acc[t][1] = (float4v){0.f, 0.f, 0.f, 0.f};
    }

    const float G[4] = {-2.f, -2.f / 3.f, 2.f / 3.f, 2.f};

    // ---- fused RBF + SiLU over this wave's K-half chunks ----
    #pragma unroll
    for (int seg = 0; seg < NSEG; seg++) {
        const void* Xp = (seg == 0) ? X0 : (seg == 1) ? X1 : X2;
        int str = (seg == 0) ? s0 : (seg == 1) ? s1 : s2;
        bool f32 = ((F32MASK >> seg) & 1) != 0;
        #pragma unroll
        for (int i = 0; i < 4; i++) {
            if (((seg * 4 + i) & 1) != kk) continue;
            int d0 = i * 32 + q * 8;
            float xa[8], xb8[8];
            loadc8(f32, Xp, (size_t)rA * str + d0, xa);
            loadc8(f32, Xp, (size_t)rB * str + d0, xb8);
            float4 gv0 = *(const float4*)(lng + seg * 128 + d0);
            float4 gv1 = *(const float4*)(lng + seg * 128 + d0 + 4);
            float4 bv0 = *(const float4*)(lnb + seg * 128 + d0);
            float4 bv1 = *(const float4*)(lnb + seg * 128 + d0 + 4);
            float gvs[8] = {gv0.x, gv0.y, gv0.z, gv0.w, gv1.x, gv1.y, gv1.z, gv1.w};
            float bvs[8] = {bv0.x, bv0.y, bv0.z, bv0.w, bv1.x, bv1.y, bv1.z, bv1.w};
            float za[8], zb[8];
            #pragma unroll
            for (int j = 0; j < 8; j++) {
                za[j] = (xa[j] - muA) * scA * gvs[j] + bvs[j];
                zb[j] = (xb8[j] - muB) * scB * gvs[j] + bvs[j];
            }
            // RBF: 4 grid points
            #pragma unroll
            for (int g = 0; g < 4; g++) {
                float ea[8], eb[8];
                #pragma unroll
                for (int j = 0; j < 8; j++) {
                    float da = (za[j] - G[g]) * 0.75f;
                    ea[j] = __expf(-da * da);
                    float db = (zb[j] - G[g]) * 0.75f;
                    eb[j] = __expf(-db * db);
                }
                f16x8 afa = pack8h(ea);
                f16x8 afb = pack8h(eb);
                int kbase = seg * 512 + g * 128 + i * 32;
                #pragma unroll
                for (int t = 0; t < NT; t++) {
                    int n = t * 16 + m;
                    f16x8 bfr = (f16x8)(_Float16)0;
                    if ((DOUT % 16 == 0) || (n < DOUT))
                        bfr = *(const f16x8*)(Wc + (size_t)n * KW + kbase + q * 8);
                    acc[t][0] = __builtin_amdgcn_mfma_f32_16x16x32_f16(afa, bfr, acc[t][0], 0, 0, 0);
                    acc[t][1] = __builtin_amdgcn_mfma_f32_16x16x32_f16(afb, bfr, acc[t][1], 0, 0, 0);
                }
            }
            // SiLU: same x registers, no reload
            {
                float ea[8], eb[8];
                #pragma unroll
                for (int j = 0; j < 8; j++) {
                    float sa = 1.0f / (1.0f + __expf(-xa[j]));
                    ea[j] = xa[j] * sa;
                    float sb = 1.0f / (1.0f + __expf(-xb8[j]));
                    eb[j] = xb8[j] * sb;
                }
                f16x8 afa = pack8h(ea);
                f16x8 afb = pack8h(eb);
                int kbase = 4 * DIN + seg * 128 + i * 32;
                #pragma unroll
                for (int t = 0; t < NT; t++) {
                    int n = t * 16 + m;
                    f16x8 bfr = (f16x8)(_Float16)0;
                    if ((DOUT % 16 == 0) || (n < DOUT))
                        bfr = *(const f16x8*)(Wc + (size_t)n * KW + kbase + q * 8);
                    acc[t][0] = __builtin_amdgcn_mfma_f32_16x16x32_f16(afa, bfr, acc[t][0], 0, 0, 0);
                    acc[t][1] = __builtin_amdgcn_mfma_f32_16x16x32_f16(afb, bfr, acc[t][1], 0, 0, 0);
                }
            }
        }
    }

    // ---- cross-wave K-half reduction (2 barriers, self-ordered LDS reuse) ----
    if (kk == 1) {
        #pragma unroll
        for (int t = 0; t < NT; t++)
            #pragma unroll
            for (int j = 0; j < 4; j++) red[r][t][j][lane] = acc[t][0][j];
    }
    __syncthreads();
    if (kk == 0) {
        #pragma unroll
        for (int t = 0; t < NT; t++)
            #pragma unroll
            for (int j = 0; j < 4; j++) {
                acc[t][0][j] += red[r][t][j][lane];  // full group-A sum
                red[r][t][j][lane] = acc[t][1][j];   // hand B partial to the k=1 wave
            }
    }
    __syncthreads();
    if (kk == 1) {
        #pragma unroll
        for (int t = 0; t < NT; t++)
            #pragma unroll
            for (int j = 0; j < 4; j++) acc[t][1][j] += red[r][t][j][lane];  // full group-B sum
    }

    // ---- epilogue: kk=0 stores group A, kk=1 stores group B (C/D: col=lane&15, row=q*4+j) ----
    int gbase = (kk == 0) ? baseA : baseB;
    float dd[4];
    #pragma unroll
    for (int j = 0; j < 4; j++) {
        int row = gbase + q * 4 + j;
        dd[j] = (row < nrows) ? dinv[row] : 0.f;
    }
    if (kk == 0) {
        #pragma unroll
        for (int t = 0; t < NT; t++) {
            int col = t * 16 + m;
            if ((DOUT % 16 == 0) || (col < DOUT)) {
                float bias = bs[col] + bb[col];
                #pragma unroll
                for (int j = 0; j < 4; j++) {
                    int row = gbase + q * 4 + j;
                    if (row < nrows) H[(size_t)row * hstride + col] = f2h((acc[t][0][j] + bias) * dd[j]);
                }
            }
        }
    } else {
        #pragma unroll
        for (int t = 0; t < NT; t++) {
            int col = t * 16 + m;
            if ((DOUT % 16 == 0) || (col < DOUT)) {
                float bias = bs[col] + bb[col];
                #pragma unroll
                for (int j = 0; j < 4; j++) {
                    int row = gbase + q * 4 + j;
                    if (row < nrows) H[(size_t)row * hstride + col] = f2h((acc[t][1][j] + bias) * dd[j]);
                }
            }
        }
    }
}

// ---------------- aggregation: wave per node, 8 edge-streams in flight ----------------
// H (f16) is pre-scaled by dinv[src]. out = dinv[wid]*(H[wid] + sum_nbr H[s]) + bg.
// Round-6: 2-deep manual edge pipelining (pairs e, e+4) -> 8 independent L3 gather
// streams per wave instead of 4 (agg was latency-bound on colv->H chains).

__global__ __launch_bounds__(256) void agg128_kernel(
    const ushortT* __restrict__ H, ushortT* __restrict__ OUT,
    const float* __restrict__ bg, const int* __restrict__ rowptr,
    const int* __restrict__ colv, const float* __restrict__ dinv,
    float2* __restrict__ STout, int n) {
    int wid = (blockIdx.x * 256 + threadIdx.x) >> 6;
    int lane = threadIdx.x & 63;
    if (wid >= n) return;
    int g = lane >> 4, t = lane & 15;
    float di = dinv[wid];
    float a[8] = {0.f, 0.f, 0.f, 0.f, 0.f, 0.f, 0.f, 0.f};
    if (g == 0) unpack_add(*(const uint4*)(H + (size_t)wid * 128 + t * 8), a);  // self
    int e0 = rowptr[wid], e1 = rowptr[wid + 1];
    int e = e0 + g;
    for (; e + 4 < e1; e += 8) {
        int s0i = colv[e], s1i = colv[e + 4];
        uint4 v0 = *(const uint4*)(H + (size_t)s0i * 128 + t * 8);
        uint4 v1 = *(const uint4*)(H + (size_t)s1i * 128 + t * 8);
        unpack_add(v0, a);
        unpack_add(v1, a);
    }
    if (e < e1) {
        unpack_add(*(const uint4*)(H + (size_t)colv[e] * 128 + t * 8), a);
    }
    #pragma unroll
    for (int j = 0; j < 8; j++) {
        a[j] += __shfl_xor(a[j], 16);
        a[j] += __shfl_xor(a[j], 32);
    }
    if (g == 0) {
        float4 b0 = *(const float4*)(bg + t * 8);
        float4 b1 = *(const float4*)(bg + t * 8 + 4);
        float bgs[8] = {b0.x, b0.y, b0.z, b0.w, b1.x, b1.y, b1.z, b1.w};
        unsigned rb[8];
        float s = 0.f, ss = 0.f;
        #pragma unroll
        for (int j = 0; j < 8; j++) {
            float o = di * a[j] + bgs[j];
            rb[j] = f2h(o);                       // RTNE; stored value
            float back = h2f((unsigned short)rb[j]);
            s += back; ss += back * back;         // stats of STORED values (LN consistency)
        }
        uint4 pk;
        pk.x = rb[0] | (rb[1] << 16);
        pk.y = rb[2] | (rb[3] << 16);
        pk.z = rb[4] | (rb[5] << 16);
        pk.w = rb[6] | (rb[7] << 16);
        *(uint4*)(OUT + (size_t)wid * 128 + t * 8) = pk;
        #pragma unroll
        for (int d = 1; d < 16; d <<= 1) { s += __shfl_xor(s, d); ss += __shfl_xor(ss, d); }
        if (t == 0) STout[wid] = make_float2(s, ss);
    }
}

// H stride 64 (cols 47..63 junk, never written out). 16 edge-streams in flight.
__global__ __launch_bounds__(256) void agg47_kernel(
    const ushortT* __restrict__ H, float* __restrict__ OUT,
    const float* __restrict__ bg, const int* __restrict__ rowptr,
    const int* __restrict__ colv, const float* __restrict__ dinv, int n) {
    int wid = (blockIdx.x * 256 + threadIdx.x) >> 6;
    int lane = threadIdx.x & 63;
    if (wid >= n) return;
    int g = lane >> 3, t = lane & 7;
    float di = dinv[wid];
    float a[8] = {0.f, 0.f, 0.f, 0.f, 0.f, 0.f, 0.f, 0.f};
    if (g == 0) unpack_add(*(const uint4*)(H + (size_t)wid * 64 + t * 8), a);  // self
    int e0 = rowptr[wid], e1 = rowptr[wid + 1];
    int e = e0 + g;
    for (; e + 8 < e1; e += 16) {
        int s0i = colv[e], s1i = colv[e + 8];
        uint4 v0 = *(const uint4*)(H + (size_t)s0i * 64 + t * 8);
        uint4 v1 = *(const uint4*)(H + (size_t)s1i * 64 + t * 8);
        unpack_add(v0, a);
        unpack_add(v1, a);
    }
    if (e < e1) {
        unpack_add(*(const uint4*)(H + (size_t)colv[e] * 64 + t * 8), a);
    }
    #pragma unroll
    for (int j = 0; j < 8; j++) {
        a[j] += __shfl_xor(a[j], 8);
        a[j] += __shfl_xor(a[j], 16);
        a[j] += __shfl_xor(a[j], 32);
    }
    if (g == 0) {
        #pragma unroll
        for (int j = 0; j < 8; j++) {
            int c = t * 8 + j;
            if (c < 47) OUT[(size_t)wid * 47 + c] = di * a[j] + bg[c];
        }
    }
}

// ---------------- launcher ----------------

extern "C" void kernel_launch(void* const* d_in, const int* in_sizes, int n_in,
                              void* d_out, int out_size, void* d_ws, size_t ws_size,
                              hipStream_t stream) {
    const float* x = (const float*)d_in[0];
    const int* ei = (const int*)d_in[1];
    const float* lng0 = (const float*)d_in[2];
    const float* lnb0 = (const float*)d_in[3];
    const float* Ws0 = (const float*)d_in[4];
    const float* bs0 = (const float*)d_in[5];
    const float* Wb0 = (const float*)d_in[6];
    const float* bb0 = (const float*)d_in[7];
    const float* bg0 = (const float*)d_in[8];
    const float* lng1 = (const float*)d_in[9];
    const float* lnb1 = (const float*)d_in[10];
    const float* Ws1 = (const float*)d_in[11];
    const float* bs1 = (const float*)d_in[12];
    const float* Wb1 = (const float*)d_in[13];
    const float* bb1 = (const float*)d_in[14];
    const float* bg1 = (const float*)d_in[15];
    const float* lng2 = (const float*)d_in[16];
    const float* lnb2 = (const float*)d_in[17];
    const float* Ws2 = (const float*)d_in[18];
    const float* bs2 = (const float*)d_in[19];
    const float* Wb2 = (const float*)d_in[20];
    const float* bb2 = (const float*)d_in[21];
    const float* bg2 = (const float*)d_in[22];

    const int N = in_sizes[0] / 128;
    const int E = in_sizes[1] / 2;
    const int NB = (N + 255) >> 8;  // coarse buckets of 256 nodes (requires N < 2^24)

    char* wsp = (char*)d_ws;
    size_t off = 0;
    auto alloc = [&](size_t bytes) {
        off = (off + 255) & ~(size_t)255;
        void* p = wsp + off;
        off += bytes;
        return p;
    };
    int* ghist = (int*)alloc(512 * 4);
    int* bbase = (int*)alloc(513 * 4);
    int* gcur = (int*)alloc(512 * 4);
    int* rowptr = (int*)alloc((size_t)(N + 1) * 4);
    int* colv = (int*)alloc((size_t)E * 4);
    float* dinvv = (float*)alloc((size_t)N * 4);
    ushortT* hbuf = (ushortT*)alloc((size_t)N * 128 * 2);
    ushortT* a1 = (ushortT*)alloc((size_t)N * 128 * 2);
    ushortT* a2 = (ushortT*)alloc((size_t)N * 128 * 2);
    float2* stx = (float2*)alloc((size_t)N * 8);
    float2* st1 = (float2*)alloc((size_t)N * 8);
    float2* st2 = (float2*)alloc((size_t)N * 8);
    ushortT* Wc0 = (ushortT*)alloc((size_t)128 * 640 * 2);
    ushortT* Wc1 = (ushortT*)alloc((size_t)128 * 640 * 2);
    ushortT* Wc2 = (ushortT*)alloc((size_t)47 * 1920 * 2);
    size_t off_base = off;
    ushortT* xb = (ushortT*)alloc((size_t)N * 128 * 2);  // f16 mirror of x
    bool fits = (off <= ws_size);
    if (!fits) off = off_base;
    (void)n_in; (void)out_size;

    // pairs staging aliases hbuf: pairs is dead before the first fkan writes hbuf.
    unsigned* pairs = (unsigned*)hbuf;

    const int* srcp = ei;
    const int* dstp = ei + E;

    int gF = (N + 63) / 64;
    int gW = (N + 3) / 4;
    int gScat = (E + SCAT_CH - 1) / SCAT_CH;

    build_wc<<<(128 * 640 + 255) / 256, 256, 0, stream>>>(Ws0, Wb0, Wc0, 128, 128);
    build_wc<<<(128 * 640 + 255) / 256, 256, 0, stream>>>(Ws1, Wb1, Wc1, 128, 128);
    build_wc<<<(47 * 1920 + 255) / 256, 256, 0, stream>>>(Ws2, Wb2, Wc2, 47, 384);

    // CSR build: coarse hist -> scan -> coarse scatter (packed pairs) -> fine per-bucket CSR
    zero_ints<<<2, 256, 0, stream>>>(ghist, 512);
    coarse_hist<<<NB, 256, 0, stream>>>(dstp, ghist, E, NB);
    bucket_scan<<<1, 64, 0, stream>>>(ghist, bbase, gcur, NB);
    coarse_scatter<<<gScat, 256, 0, stream>>>(srcp, dstp, gcur, pairs, E, NB);
    fine_csr<<<NB, 256, 0, stream>>>(pairs, bbase, rowptr, colv, dinvv, N, E);

    stats_f32<<<gW, 256, 0, stream>>>(x, stx, fits ? xb : nullptr, N);

    // layer 1
    if (fits)
        fkan_kernel<1, 128, 0><<<gF, 256, 0, stream>>>(xb, 128, xb, 128, xb, 128, stx, stx, stx,
                                                       lng0, lnb0, Wc0, bs0, bb0, dinvv, hbuf, 128, N);
    else
        fkan_kernel<1, 128, 1><<<gF, 256, 0, stream>>>(x, 128, x, 128, x, 128, stx, stx, stx,
                                                       lng0, lnb0, Wc0, bs0, bb0, dinvv, hbuf, 128, N);
    agg128_kernel<<<gW, 256, 0, stream>>>(hbuf, a1, bg0, rowptr, colv, dinvv, st1, N);

    // layer 2
    fkan_kernel<1, 128, 0><<<gF, 256, 0, stream>>>(a1, 128, a1, 128, a1, 128, st1, st1, st1,
                                                   lng1, lnb1, Wc1, bs1, bb1, dinvv, hbuf, 128, N);
    agg128_kernel<<<gW, 256, 0, stream>>>(hbuf, a2, bg1, rowptr, colv, dinvv, st2, N);

    // layer 3 (hbuf stride 64)
    if (fits)
        fkan_kernel<3, 47, 0><<<gF, 256, 0, stream>>>(xb, 128, a1, 128, a2, 128, stx, st1, st2,
                                                      lng2, lnb2, Wc2, bs2, bb2, dinvv, hbuf, 64, N);
    else
        fkan_kernel<3, 47, 1><<<gF, 256, 0, stream>>>(x, 128, a1, 128, a2, 128, stx, st1, st2,
                                                      lng2, lnb2, Wc2, bs2, bb2, dinvv, hbuf, 64, N);
    agg47_kernel<<<gW, 256, 0, stream>>>(hbuf, (float*)d_out, bg2, rowptr, colv, dinvv, N);
}

// Round 7
// 691.374 us; speedup vs baseline: 1.2735x; 1.0417x over previous
//
#include <hip/hip_runtime.h>
#include <hip/hip_fp16.h>

typedef unsigned short ushortT;
typedef _Float16 f16x8 __attribute__((ext_vector_type(8)));
typedef __attribute__((ext_vector_type(4))) float float4v;
typedef __attribute__((ext_vector_type(4))) unsigned int uint4v;

__device__ __forceinline__ unsigned short f2h(float f) {  // RTNE f32->f16 (v_cvt_f16_f32)
    _Float16 h = (_Float16)f;
    return __builtin_bit_cast(unsigned short, h);
}
__device__ __forceinline__ float h2f(unsigned short b) {  // v_cvt_f32_f16
    return (float)__builtin_bit_cast(_Float16, b);
}
// packed f32x2 -> f16x2, RTZ (v_cvt_pkrtz_f16_f32, 1 inst).
__device__ __forceinline__ unsigned pkrtz(float lo, float hi) {
    auto h = __builtin_amdgcn_cvt_pkrtz(lo, hi);
    return __builtin_bit_cast(unsigned, h);
}
__device__ __forceinline__ void unpack_add(uint4 v, float a[8]) {  // f16 pairs
    unsigned uu[4] = {v.x, v.y, v.z, v.w};
    #pragma unroll
    for (int j = 0; j < 8; j++) a[j] += h2f((unsigned short)(uu[j >> 1] >> ((j & 1) * 16)));
}

// 8-element row load; f32 flag folds at compile time. Also returns the RAW f16 pairs
// (for f32 inputs: packed via pkrtz) so SiLU can run packed without re-packing.
__device__ __forceinline__ void loadc8r(bool f32, const void* p, size_t off, float o[8], uint4& raw) {
    if (f32) {
        const float* q = (const float*)p + off;
        float4 a = *(const float4*)q;
        float4 b = *(const float4*)(q + 4);
        o[0] = a.x; o[1] = a.y; o[2] = a.z; o[3] = a.w;
        o[4] = b.x; o[5] = b.y; o[6] = b.z; o[7] = b.w;
        raw.x = pkrtz(a.x, a.y); raw.y = pkrtz(a.z, a.w);
        raw.z = pkrtz(b.x, b.y); raw.w = pkrtz(b.z, b.w);
    } else {
        uint4 v = *(const uint4*)((const ushortT*)p + off);
        raw = v;
        unsigned uu[4] = {v.x, v.y, v.z, v.w};
        #pragma unroll
        for (int j = 0; j < 8; j++) o[j] = h2f((unsigned short)(uu[j >> 1] >> ((j & 1) * 16)));
    }
}

// ---------------- combined weight build: Wc[n][seg*512+g*128+dl | 4*DIN+d] (f16) ----------------
__global__ __launch_bounds__(256) void build_wc(const float* __restrict__ Ws, const float* __restrict__ Wb,
                                                ushortT* __restrict__ Wc, int dout, int din) {
    int idx = blockIdx.x * 256 + threadIdx.x;
    int kw = 5 * din;
    if (idx >= dout * kw) return;
    int n = idx / kw, c = idx % kw;
    float v;
    if (c < 4 * din) {
        int seg = c >> 9;
        int rem = c & 511;
        int g = rem >> 7;
        int dl = rem & 127;
        v = Ws[(size_t)n * 4 * din + 4 * (seg * 128 + dl) + g];
    } else {
        v = Wb[(size_t)n * din + (c - 4 * din)];
    }
    Wc[idx] = f2h(v);
}

// ---------------- per-row LN stats for f32 x (+ optional f16 mirror) ----------------

__global__ __launch_bounds__(256) void stats_f32(const float* __restrict__ X, float2* __restrict__ ST,
                                                 ushortT* __restrict__ xb, int n) {
    int wid = (blockIdx.x * 256 + threadIdx.x) >> 6;
    int lane = threadIdx.x & 63;
    if (wid >= n) return;
    float2 v = *(const float2*)(X + (size_t)wid * 128 + lane * 2);
    if (xb) {
        *(unsigned*)(xb + (size_t)wid * 128 + lane * 2) = pkrtz(v.x, v.y);
    }
    float s = v.x + v.y, ss = v.x * v.x + v.y * v.y;
    #pragma unroll
    for (int d = 1; d < 64; d <<= 1) { s += __shfl_xor(s, d); ss += __shfl_xor(ss, d); }
    if (lane == 0) ST[wid] = make_float2(s, ss);
}

// ---------------- CSR build: two-level counting sort ----------------
// Pack: src (bits 0..23, N < 2^24) | (dst & 255) << 24. Coarse bucket = dst >> 8.

__global__ __launch_bounds__(256) void zero_ints(int* p, int n) {
    int i = blockIdx.x * 256 + threadIdx.x;
    if (i < n) p[i] = 0;
}

__device__ __forceinline__ int wave_incl_scan(int v, int lane) {
    #pragma unroll
    for (int d = 1; d < 64; d <<= 1) {
        int o = __shfl_up(v, d);
        if (lane >= d) v += o;
    }
    return v;
}

// coarse histogram of dst>>8 (LDS-staged; ~nb global atomics per block)
__global__ __launch_bounds__(256) void coarse_hist(const int* __restrict__ dst, int* __restrict__ ghist,
                                                   int E, int nb) {
    __shared__ int h[512];
    for (int i = threadIdx.x; i < 512; i += 256) h[i] = 0;
    __syncthreads();
    int stride = gridDim.x * 256;
    for (int e = blockIdx.x * 256 + threadIdx.x; e < E; e += stride) {
        atomicAdd(&h[dst[e] >> 8], 1);
    }
    __syncthreads();
    for (int i = threadIdx.x; i < nb; i += 256) {
        int c = h[i];
        if (c) atomicAdd(&ghist[i], c);
    }
}

// exclusive scan of nb (<=512) bucket counts; writes base[0..nb] and a working copy gcur
__global__ __launch_bounds__(64) void bucket_scan(const int* __restrict__ ghist, int* __restrict__ base,
                                                  int* __restrict__ gcur, int nb) {
    int lane = threadIdx.x;
    int carry = 0;
    for (int b0 = 0; b0 < nb; b0 += 64) {
        int i = b0 + lane;
        int v = (i < nb) ? ghist[i] : 0;
        int incl = wave_incl_scan(v, lane);
        if (i < nb) { int ex = carry + incl - v; base[i] = ex; gcur[i] = ex; }
        carry += __shfl(incl, 63);
    }
    if (lane == 0) base[nb] = carry;
}

// bin edges into coarse buckets. Per block: LDS hist of its chunk, ONE global atomic per
// (block,bucket) to reserve a contiguous run, then LDS-cursor scatter -> runs of ~10 words.
#define SCAT_CH 4096
__global__ __launch_bounds__(256) void coarse_scatter(const int* __restrict__ src, const int* __restrict__ dst,
                                                      int* __restrict__ gcur, unsigned* __restrict__ pairs,
                                                      int E, int nb) {
    __shared__ int cur[512];
    for (int i = threadIdx.x; i < 512; i += 256) cur[i] = 0;
    __syncthreads();
    int e0 = blockIdx.x * SCAT_CH;
    int e1 = min(e0 + SCAT_CH, E);
    for (int e = e0 + threadIdx.x; e < e1; e += 256) atomicAdd(&cur[dst[e] >> 8], 1);
    __syncthreads();
    for (int i = threadIdx.x; i < nb; i += 256) {
        int c = cur[i];
        cur[i] = c ? atomicAdd(&gcur[i], c) : 0;
    }
    __syncthreads();
    for (int e = e0 + threadIdx.x; e < e1; e += 256) {
        int d = dst[e];
        int r = atomicAdd(&cur[d >> 8], 1);
        pairs[r] = (unsigned)src[e] | ((unsigned)(d & 255) << 24);
    }
}

// one block per coarse bucket: fine 256-bin hist -> rowptr + dinv, then scatter colv
// entirely inside the bucket's contiguous output window (full line utilization).
__global__ __launch_bounds__(256) void fine_csr(const unsigned* __restrict__ pairs, const int* __restrict__ base,
                                                int* __restrict__ rowptr, int* __restrict__ colv,
                                                float* __restrict__ dinv, int n, int E) {
    __shared__ int h[256];
    __shared__ int cur[256];
    __shared__ int wt[4];
    int b = blockIdx.x, tid = threadIdx.x;
    int e0 = base[b], e1 = base[b + 1];
    h[tid] = 0;
    __syncthreads();
    for (int e = e0 + tid; e < e1; e += 256) atomicAdd(&h[pairs[e] >> 24], 1);
    __syncthreads();
    int v = h[tid];
    int lane = tid & 63, w = tid >> 6;
    int incl = wave_incl_scan(v, lane);
    if (lane == 63) wt[w] = incl;
    __syncthreads();
    int woff = 0;
    for (int i = 0; i < w; i++) woff += wt[i];
    int excl = woff + incl - v;
    int node = b * 256 + tid;
    if (node < n) {
        rowptr[node] = e0 + excl;
        dinv[node] = rsqrtf((float)(v + 1));  // +1 self loop
        if (node == n - 1) rowptr[n] = E;
    }
    cur[tid] = e0 + excl;
    __syncthreads();
    for (int e = e0 + tid; e < e1; e += 256) {
        unsigned p = pairs[e];
        int r = atomicAdd(&cur[p >> 24], 1);
        colv[r] = (int)(p & 0x00FFFFFFu);
    }
}

// ---------------- fused FastKAN transform (f16 MFMA, packed-f16 activation math) ----------------
// Block = 64 rows, 4 waves = 2 row-panels x 2 K-halves; each wave keeps 2 row-groups
// sharing each Wc B-fragment (round-3) + K-split occupancy (round-4) + single-pass
// RBF/SiLU from one X load (round-6).
// Round-7: RBF/SiLU element math in packed __half2 (v_pk_* + v_exp_f16): exp2-folded
//   zc = z*(0.75*sqrt(log2 e)); per grid: pk_sub, pk_mul(-d*d), h2exp2 -> result IS the
//   packed MFMA fragment pair. SiLU from raw f16 pairs: pk_mul(-log2e), h2exp2, pk_add,
//   h2rcp, pk_mul. LN stays f32 (f16 LN triples z error - analysis r7).
template <int NSEG, int DOUT, int F32MASK>
__global__ __launch_bounds__(256) void fkan_kernel(
    const void* __restrict__ X0, int s0,
    const void* __restrict__ X1, int s1,
    const void* __restrict__ X2, int s2,
    const float2* __restrict__ ST0, const float2* __restrict__ ST1, const float2* __restrict__ ST2,
    const float* __restrict__ lng, const float* __restrict__ lnb,
    const ushortT* __restrict__ Wc,
    const float* __restrict__ bs, const float* __restrict__ bb,
    const float* __restrict__ dinv,
    ushortT* __restrict__ H, int hstride, int nrows) {
    constexpr int DIN = NSEG * 128;
    constexpr int KW = 5 * DIN;
    constexpr int NT = (DOUT + 15) / 16;
    __shared__ float red[2][NT][4][64];  // [panel][tile][reg][lane]
    int tid = threadIdx.x;
    int w = tid >> 6, lane = tid & 63;
    int m = lane & 15, q = lane >> 4;
    int r = w & 1;    // row panel
    int kk = w >> 1;  // K half
    int baseA = blockIdx.x * 64 + r * 16;
    int baseB = baseA + 32;
    int rA = min(baseA + m, nrows - 1);
    int rB = min(baseB + m, nrows - 1);

    float muA, scA, muB, scB;
    {
        float2 st = ST0[rA]; float sum = st.x, ssq = st.y;
        if (NSEG == 3) { float2 t1 = ST1[rA]; sum += t1.x; ssq += t1.y; float2 t2 = ST2[rA]; sum += t2.x; ssq += t2.y; }
        muA = sum * (1.0f / DIN);
        float var = ssq * (1.0f / DIN) - muA * muA;
        scA = rsqrtf(fmaxf(var, 0.0f) + 1e-5f);
    }
    {
        float2 st = ST0[rB]; float sum = st.x, ssq = st.y;
        if (NSEG == 3) { float2 t1 = ST1[rB]; sum += t1.x; ssq += t1.y; float2 t2 = ST2[rB]; sum += t2.x; ssq += t2.y; }
        muB = sum * (1.0f / DIN);
        float var = ssq * (1.0f / DIN) - muB * muB;
        scB = rsqrtf(fmaxf(var, 0.0f) + 1e-5f);
    }

    float4v acc[NT][2];
    #pragma unroll
    for (int t = 0; t < NT; t++) {
        acc[t][0] = (float4v){0.f, 0.f, 0.f, 0.f};
        acc[t][1] = (float4v){0.f, 0.f, 0.f, 0.f};
    }

    // exp(-((z-G)*0.75)^2) == exp2(-(zc-Gc)^2), zc=z*CC, Gc=G*CC, CC=0.75*sqrt(log2 e)
    const float CC = 0.90084159f;
    const __half2 Gc2[4] = {
        __float2half2_rn(-2.f * CC), __float2half2_rn(-2.f / 3.f * CC),
        __float2half2_rn(2.f / 3.f * CC), __float2half2_rn(2.f * CC)};
    const __half2 NL2E = __float2half2_rn(-1.44269504f);
    const __half2 ONE2 = __float2half2_rn(1.0f);

    // ---- fused RBF + SiLU over this wave's K-half chunks ----
    #pragma unroll
    for (int seg = 0; seg < NSEG; seg++) {
        const void* Xp = (seg == 0) ? X0 : (seg == 1) ? X1 : X2;
        int str = (seg == 0) ? s0 : (seg == 1) ? s1 : s2;
        bool f32 = ((F32MASK >> seg) & 1) != 0;
        #pragma unroll
        for (int i = 0; i < 4; i++) {
            if (((seg * 4 + i) & 1) != kk) continue;
            int d0 = i * 32 + q * 8;
            float xa[8], xb8[8];
            uint4 rawA, rawB;
            loadc8r(f32, Xp, (size_t)rA * str + d0, xa, rawA);
            loadc8r(f32, Xp, (size_t)rB * str + d0, xb8, rawB);
            float4 gv0 = *(const float4*)(lng + seg * 128 + d0);
            float4 gv1 = *(const float4*)(lng + seg * 128 + d0 + 4);
            float4 bv0 = *(const float4*)(lnb + seg * 128 + d0);
            float4 bv1 = *(const float4*)(lnb + seg * 128 + d0 + 4);
            float gvs[8] = {gv0.x, gv0.y, gv0.z, gv0.w, gv1.x, gv1.y, gv1.z, gv1.w};
            float bvs[8] = {bv0.x, bv0.y, bv0.z, bv0.w, bv1.x, bv1.y, bv1.z, bv1.w};
            float za[8], zb[8];
            #pragma unroll
            for (int j = 0; j < 8; j++) {
                za[j] = (xa[j] - muA) * scA * gvs[j] + bvs[j];
                zb[j] = (xb8[j] - muB) * scB * gvs[j] + bvs[j];
            }
            // pack zc = z*CC
            __half2 zhA[4], zhB[4];
            #pragma unroll
            for (int p = 0; p < 4; p++) {
                zhA[p] = __builtin_bit_cast(__half2, pkrtz(za[2 * p] * CC, za[2 * p + 1] * CC));
                zhB[p] = __builtin_bit_cast(__half2, pkrtz(zb[2 * p] * CC, zb[2 * p + 1] * CC));
            }
            // RBF: 4 grid points, packed f16; exp output IS the fragment pair
            #pragma unroll
            for (int g = 0; g < 4; g++) {
                uint4v ua, ub;
                #pragma unroll
                for (int p = 0; p < 4; p++) {
                    __half2 dA = __hsub2(zhA[p], Gc2[g]);
                    ua[p] = __builtin_bit_cast(unsigned, h2exp2(__hmul2(dA, __hneg2(dA))));
                    __half2 dB = __hsub2(zhB[p], Gc2[g]);
                    ub[p] = __builtin_bit_cast(unsigned, h2exp2(__hmul2(dB, __hneg2(dB))));
                }
                f16x8 afa = __builtin_bit_cast(f16x8, ua);
                f16x8 afb = __builtin_bit_cast(f16x8, ub);
                int kbase = seg * 512 + g * 128 + i * 32;
                #pragma unroll
                for (int t = 0; t < NT; t++) {
                    int n = t * 16 + m;
                    f16x8 bfr = (f16x8)(_Float16)0;
                    if ((DOUT % 16 == 0) || (n < DOUT))
                        bfr = *(const f16x8*)(Wc + (size_t)n * KW + kbase + q * 8);
                    acc[t][0] = __builtin_amdgcn_mfma_f32_16x16x32_f16(afa, bfr, acc[t][0], 0, 0, 0);
                    acc[t][1] = __builtin_amdgcn_mfma_f32_16x16x32_f16(afb, bfr, acc[t][1], 0, 0, 0);
                }
            }
            // SiLU from raw f16 pairs: x * 1/(1 + exp2(-x*log2e))
            {
                unsigned raA[4] = {rawA.x, rawA.y, rawA.z, rawA.w};
                unsigned raB[4] = {rawB.x, rawB.y, rawB.z, rawB.w};
                uint4v ua, ub;
                #pragma unroll
                for (int p = 0; p < 4; p++) {
                    __half2 xhA = __builtin_bit_cast(__half2, raA[p]);
                    __half2 sgA = h2rcp(__hadd2(ONE2, h2exp2(__hmul2(xhA, NL2E))));
                    ua[p] = __builtin_bit_cast(unsigned, __hmul2(xhA, sgA));
                    __half2 xhB = __builtin_bit_cast(__half2, raB[p]);
                    __half2 sgB = h2rcp(__hadd2(ONE2, h2exp2(__hmul2(xhB, NL2E))));
                    ub[p] = __builtin_bit_cast(unsigned, __hmul2(xhB, sgB));
                }
                f16x8 afa = __builtin_bit_cast(f16x8, ua);
                f16x8 afb = __builtin_bit_cast(f16x8, ub);
                int kbase = 4 * DIN + seg * 128 + i * 32;
                #pragma unroll
                for (int t = 0; t < NT; t++) {
                    int n = t * 16 + m;
                    f16x8 bfr = (f16x8)(_Float16)0;
                    if ((DOUT % 16 == 0) || (n < DOUT))
                        bfr = *(const f16x8*)(Wc + (size_t)n * KW + kbase + q * 8);
                    acc[t][0] = __builtin_amdgcn_mfma_f32_16x16x32_f16(afa, bfr, acc[t][0], 0, 0, 0);
                    acc[t][1] = __builtin_amdgcn_mfma_f32_16x16x32_f16(afb, bfr, acc[t][1], 0, 0, 0);
                }
            }
        }
    }

    // ---- cross-wave K-half reduction (2 barriers, self-ordered LDS reuse) ----
    if (kk == 1) {
        #pragma unroll
        for (int t = 0; t < NT; t++)
            #pragma unroll
            for (int j = 0; j < 4; j++) red[r][t][j][lane] = acc[t][0][j];
    }
    __syncthreads();
    if (kk == 0) {
        #pragma unroll
        for (int t = 0; t < NT; t++)
            #pragma unroll
            for (int j = 0; j < 4; j++) {
                acc[t][0][j] += red[r][t][j][lane];  // full group-A sum
                red[r][t][j][lane] = acc[t][1][j];   // hand B partial to the k=1 wave
            }
    }
    __syncthreads();
    if (kk == 1) {
        #pragma unroll
        for (int t = 0; t < NT; t++)
            #pragma unroll
            for (int j = 0; j < 4; j++) acc[t][1][j] += red[r][t][j][lane];  // full group-B sum
    }

    // ---- epilogue: kk=0 stores group A, kk=1 stores group B (C/D: col=lane&15, row=q*4+j) ----
    int gbase = (kk == 0) ? baseA : baseB;
    float dd[4];
    #pragma unroll
    for (int j = 0; j < 4; j++) {
        int row = gbase + q * 4 + j;
        dd[j] = (row < nrows) ? dinv[row] : 0.f;
    }
    if (kk == 0) {
        #pragma unroll
        for (int t = 0; t < NT; t++) {
            int col = t * 16 + m;
            if ((DOUT % 16 == 0) || (col < DOUT)) {
                float bias = bs[col] + bb[col];
                #pragma unroll
                for (int j = 0; j < 4; j++) {
                    int row = gbase + q * 4 + j;
                    if (row < nrows) H[(size_t)row * hstride + col] = f2h((acc[t][0][j] + bias) * dd[j]);
                }
            }
        }
    } else {
        #pragma unroll
        for (int t = 0; t < NT; t++) {
            int col = t * 16 + m;
            if ((DOUT % 16 == 0) || (col < DOUT)) {
                float bias = bs[col] + bb[col];
                #pragma unroll
                for (int j = 0; j < 4; j++) {
                    int row = gbase + q * 4 + j;
                    if (row < nrows) H[(size_t)row * hstride + col] = f2h((acc[t][1][j] + bias) * dd[j]);
                }
            }
        }
    }
}

// ---------------- aggregation: wave per node, 8 edge-streams in flight ----------------
// H (f16) is pre-scaled by dinv[src]. out = dinv[wid]*(H[wid] + sum_nbr H[s]) + bg.

__global__ __launch_bounds__(256) void agg128_kernel(
    const ushortT* __restrict__ H, ushortT* __restrict__ OUT,
    const float* __restrict__ bg, const int* __restrict__ rowptr,
    const int* __restrict__ colv, const float* __restrict__ dinv,
    float2* __restrict__ STout, int n) {
    int wid = (blockIdx.x * 256 + threadIdx.x) >> 6;
    int lane = threadIdx.x & 63;
    if (wid >= n) return;
    int g = lane >> 4, t = lane & 15;
    float di = dinv[wid];
    float a[8] = {0.f, 0.f, 0.f, 0.f, 0.f, 0.f, 0.f, 0.f};
    if (g == 0) unpack_add(*(const uint4*)(H + (size_t)wid * 128 + t * 8), a);  // self
    int e0 = rowptr[wid], e1 = rowptr[wid + 1];
    int e = e0 + g;
    for (; e + 4 < e1; e += 8) {
        int s0i = colv[e], s1i = colv[e + 4];
        uint4 v0 = *(const uint4*)(H + (size_t)s0i * 128 + t * 8);
        uint4 v1 = *(const uint4*)(H + (size_t)s1i * 128 + t * 8);
        unpack_add(v0, a);
        unpack_add(v1, a);
    }
    if (e < e1) {
        unpack_add(*(const uint4*)(H + (size_t)colv[e] * 128 + t * 8), a);
    }
    #pragma unroll
    for (int j = 0; j < 8; j++) {
        a[j] += __shfl_xor(a[j], 16);
        a[j] += __shfl_xor(a[j], 32);
    }
    if (g == 0) {
        float4 b0 = *(const float4*)(bg + t * 8);
        float4 b1 = *(const float4*)(bg + t * 8 + 4);
        float bgs[8] = {b0.x, b0.y, b0.z, b0.w, b1.x, b1.y, b1.z, b1.w};
        unsigned rb[8];
        float s = 0.f, ss = 0.f;
        #pragma unroll
        for (int j = 0; j < 8; j++) {
            float o = di * a[j] + bgs[j];
            rb[j] = f2h(o);                       // RTNE; stored value
            float back = h2f((unsigned short)rb[j]);
            s += back; ss += back * back;         // stats of STORED values (LN consistency)
        }
        uint4 pk;
        pk.x = rb[0] | (rb[1] << 16);
        pk.y = rb[2] | (rb[3] << 16);
        pk.z = rb[4] | (rb[5] << 16);
        pk.w = rb[6] | (rb[7] << 16);
        *(uint4*)(OUT + (size_t)wid * 128 + t * 8) = pk;
        #pragma unroll
        for (int d = 1; d < 16; d <<= 1) { s += __shfl_xor(s, d); ss += __shfl_xor(ss, d); }
        if (t == 0) STout[wid] = make_float2(s, ss);
    }
}

// H stride 64 (cols 47..63 junk, never written out). 16 edge-streams in flight.
__global__ __launch_bounds__(256) void agg47_kernel(
    const ushortT* __restrict__ H, float* __restrict__ OUT,
    const float* __restrict__ bg, const int* __restrict__ rowptr,
    const int* __restrict__ colv, const float* __restrict__ dinv, int n) {
    int wid = (blockIdx.x * 256 + threadIdx.x) >> 6;
    int lane = threadIdx.x & 63;
    if (wid >= n) return;
    int g = lane >> 3, t = lane & 7;
    float di = dinv[wid];
    float a[8] = {0.f, 0.f, 0.f, 0.f, 0.f, 0.f, 0.f, 0.f};
    if (g == 0) unpack_add(*(const uint4*)(H + (size_t)wid * 64 + t * 8), a);  // self
    int e0 = rowptr[wid], e1 = rowptr[wid + 1];
    int e = e0 + g;
    for (; e + 8 < e1; e += 16) {
        int s0i = colv[e], s1i = colv[e + 8];
        uint4 v0 = *(const uint4*)(H + (size_t)s0i * 64 + t * 8);
        uint4 v1 = *(const uint4*)(H + (size_t)s1i * 64 + t * 8);
        unpack_add(v0, a);
        unpack_add(v1, a);
    }
    if (e < e1) {
        unpack_add(*(const uint4*)(H + (size_t)colv[e] * 64 + t * 8), a);
    }
    #pragma unroll
    for (int j = 0; j < 8; j++) {
        a[j] += __shfl_xor(a[j], 8);
        a[j] += __shfl_xor(a[j], 16);
        a[j] += __shfl_xor(a[j], 32);
    }
    if (g == 0) {
        #pragma unroll
        for (int j = 0; j < 8; j++) {
            int c = t * 8 + j;
            if (c < 47) OUT[(size_t)wid * 47 + c] = di * a[j] + bg[c];
        }
    }
}

// ---------------- launcher ----------------

extern "C" void kernel_launch(void* const* d_in, const int* in_sizes, int n_in,
                              void* d_out, int out_size, void* d_ws, size_t ws_size,
                              hipStream_t stream) {
    const float* x = (const float*)d_in[0];
    const int* ei = (const int*)d_in[1];
    const float* lng0 = (const float*)d_in[2];
    const float* lnb0 = (const float*)d_in[3];
    const float* Ws0 = (const float*)d_in[4];
    const float* bs0 = (const float*)d_in[5];
    const float* Wb0 = (const float*)d_in[6];
    const float* bb0 = (const float*)d_in[7];
    const float* bg0 = (const float*)d_in[8];
    const float* lng1 = (const float*)d_in[9];
    const float* lnb1 = (const float*)d_in[10];
    const float* Ws1 = (const float*)d_in[11];
    const float* bs1 = (const float*)d_in[12];
    const float* Wb1 = (const float*)d_in[13];
    const float* bb1 = (const float*)d_in[14];
    const float* bg1 = (const float*)d_in[15];
    const float* lng2 = (const float*)d_in[16];
    const float* lnb2 = (const float*)d_in[17];
    const float* Ws2 = (const float*)d_in[18];
    const float* bs2 = (const float*)d_in[19];
    const float* Wb2 = (const float*)d_in[20];
    const float* bb2 = (const float*)d_in[21];
    const float* bg2 = (const float*)d_in[22];

    const int N = in_sizes[0] / 128;
    const int E = in_sizes[1] / 2;
    const int NB = (N + 255) >> 8;  // coarse buckets of 256 nodes (requires N < 2^24)

    char* wsp = (char*)d_ws;
    size_t off = 0;
    auto alloc = [&](size_t bytes) {
        off = (off + 255) & ~(size_t)255;
        void* p = wsp + off;
        off += bytes;
        return p;
    };
    int* ghist = (int*)alloc(512 * 4);
    int* bbase = (int*)alloc(513 * 4);
    int* gcur = (int*)alloc(512 * 4);
    int* rowptr = (int*)alloc((size_t)(N + 1) * 4);
    int* colv = (int*)alloc((size_t)E * 4);
    float* dinvv = (float*)alloc((size_t)N * 4);
    ushortT* hbuf = (ushortT*)alloc((size_t)N * 128 * 2);
    ushortT* a1 = (ushortT*)alloc((size_t)N * 128 * 2);
    ushortT* a2 = (ushortT*)alloc((size_t)N * 128 * 2);
    float2* stx = (float2*)alloc((size_t)N * 8);
    float2* st1 = (float2*)alloc((size_t)N * 8);
    float2* st2 = (float2*)alloc((size_t)N * 8);
    ushortT* Wc0 = (ushortT*)alloc((size_t)128 * 640 * 2);
    ushortT* Wc1 = (ushortT*)alloc((size_t)128 * 640 * 2);
    ushortT* Wc2 = (ushortT*)alloc((size_t)47 * 1920 * 2);
    size_t off_base = off;
    ushortT* xb = (ushortT*)alloc((size_t)N * 128 * 2);  // f16 mirror of x
    bool fits = (off <= ws_size);
    if (!fits) off = off_base;
    (void)n_in; (void)out_size;

    // pairs staging aliases hbuf: pairs is dead before the first fkan writes hbuf.
    unsigned* pairs = (unsigned*)hbuf;

    const int* srcp = ei;
    const int* dstp = ei + E;

    int gF = (N + 63) / 64;
    int gW = (N + 3) / 4;
    int gScat = (E + SCAT_CH - 1) / SCAT_CH;

    build_wc<<<(128 * 640 + 255) / 256, 256, 0, stream>>>(Ws0, Wb0, Wc0, 128, 128);
    build_wc<<<(128 * 640 + 255) / 256, 256, 0, stream>>>(Ws1, Wb1, Wc1, 128, 128);
    build_wc<<<(47 * 1920 + 255) / 256, 256, 0, stream>>>(Ws2, Wb2, Wc2, 47, 384);

    // CSR build: coarse hist -> scan -> coarse scatter (packed pairs) -> fine per-bucket CSR
    zero_ints<<<2, 256, 0, stream>>>(ghist, 512);
    coarse_hist<<<NB, 256, 0, stream>>>(dstp, ghist, E, NB);
    bucket_scan<<<1, 64, 0, stream>>>(ghist, bbase, gcur, NB);
    coarse_scatter<<<gScat, 256, 0, stream>>>(srcp, dstp, gcur, pairs, E, NB);
    fine_csr<<<NB, 256, 0, stream>>>(pairs, bbase, rowptr, colv, dinvv, N, E);

    stats_f32<<<gW, 256, 0, stream>>>(x, stx, fits ? xb : nullptr, N);

    // layer 1
    if (fits)
        fkan_kernel<1, 128, 0><<<gF, 256, 0, stream>>>(xb, 128, xb, 128, xb, 128, stx, stx, stx,
                                                       lng0, lnb0, Wc0, bs0, bb0, dinvv, hbuf, 128, N);
    else
        fkan_kernel<1, 128, 1><<<gF, 256, 0, stream>>>(x, 128, x, 128, x, 128, stx, stx, stx,
                                                       lng0, lnb0, Wc0, bs0, bb0, dinvv, hbuf, 128, N);
    agg128_kernel<<<gW, 256, 0, stream>>>(hbuf, a1, bg0, rowptr, colv, dinvv, st1, N);

    // layer 2
    fkan_kernel<1, 128, 0><<<gF, 256, 0, stream>>>(a1, 128, a1, 128, a1, 128, st1, st1, st1,
                                                   lng1, lnb1, Wc1, bs1, bb1, dinvv, hbuf, 128, N);
    agg128_kernel<<<gW, 256, 0, stream>>>(hbuf, a2, bg1, rowptr, colv, dinvv, st2, N);

    // layer 3 (hbuf stride 64)
    if (fits)
        fkan_kernel<3, 47, 0><<<gF, 256, 0, stream>>>(xb, 128, a1, 128, a2, 128, stx, st1, st2,
                                                      lng2, lnb2, Wc2, bs2, bb2, dinvv, hbuf, 64, N);
    else
        fkan_kernel<3, 47, 1><<<gF, 256, 0, stream>>>(x, 128, a1, 128, a2, 128, stx, st1, st2,
                                                      lng2, lnb2, Wc2, bs2, bb2, dinvv, hbuf, 64, N);
    agg47_kernel<<<gW, 256, 0, stream>>>(hbuf, (float*)d_out, bg2, rowptr, colv, dinvv, N);
}

// Round 8
// 678.673 us; speedup vs baseline: 1.2973x; 1.0187x over previous
//
#include <hip/hip_runtime.h>
#include <hip/hip_fp16.h>

typedef unsigned short ushortT;
typedef _Float16 f16x8 __attribute__((ext_vector_type(8)));
typedef __attribute__((ext_vector_type(4))) float float4v;
typedef __attribute__((ext_vector_type(4))) unsigned int uint4v;

__device__ __forceinline__ unsigned short f2h(float f) {  // RTNE f32->f16 (v_cvt_f16_f32)
    _Float16 h = (_Float16)f;
    return __builtin_bit_cast(unsigned short, h);
}
__device__ __forceinline__ float h2f(unsigned short b) {  // v_cvt_f32_f16
    return (float)__builtin_bit_cast(_Float16, b);
}
// packed f32x2 -> f16x2, RTZ (v_cvt_pkrtz_f16_f32, 1 inst).
__device__ __forceinline__ unsigned pkrtz(float lo, float hi) {
    auto h = __builtin_amdgcn_cvt_pkrtz(lo, hi);
    return __builtin_bit_cast(unsigned, h);
}
__device__ __forceinline__ void unpack8(uint4 v, float o[8]) {
    unsigned uu[4] = {v.x, v.y, v.z, v.w};
    #pragma unroll
    for (int j = 0; j < 8; j++) o[j] = h2f((unsigned short)(uu[j >> 1] >> ((j & 1) * 16)));
}
__device__ __forceinline__ void unpack_add(uint4 v, float a[8]) {  // f16 pairs
    unsigned uu[4] = {v.x, v.y, v.z, v.w};
    #pragma unroll
    for (int j = 0; j < 8; j++) a[j] += h2f((unsigned short)(uu[j >> 1] >> ((j & 1) * 16)));
}

// 8-element row load (f32 fallback path); also returns raw f16 pairs
__device__ __forceinline__ void loadc8r(bool f32, const void* p, size_t off, float o[8], uint4& raw) {
    if (f32) {
        const float* q = (const float*)p + off;
        float4 a = *(const float4*)q;
        float4 b = *(const float4*)(q + 4);
        o[0] = a.x; o[1] = a.y; o[2] = a.z; o[3] = a.w;
        o[4] = b.x; o[5] = b.y; o[6] = b.z; o[7] = b.w;
        raw.x = pkrtz(a.x, a.y); raw.y = pkrtz(a.z, a.w);
        raw.z = pkrtz(b.x, b.y); raw.w = pkrtz(b.z, b.w);
    } else {
        uint4 v = *(const uint4*)((const ushortT*)p + off);
        raw = v;
        unpack8(v, o);
    }
}

// ---------------- combined weight build (all 3 layers in ONE launch) ----------------
// Wc[n][seg*512+g*128+dl | 4*DIN+d] (f16). Grid: [0,320) L0, [320,640) L1, [640,993) L2.
__global__ __launch_bounds__(256) void build_wc3(
    const float* __restrict__ Ws0, const float* __restrict__ Wb0, ushortT* __restrict__ Wc0,
    const float* __restrict__ Ws1, const float* __restrict__ Wb1, ushortT* __restrict__ Wc1,
    const float* __restrict__ Ws2, const float* __restrict__ Wb2, ushortT* __restrict__ Wc2) {
    int b = blockIdx.x;
    const float *Ws, *Wb;
    ushortT* Wc;
    int dout, din, base;
    if (b < 320) { Ws = Ws0; Wb = Wb0; Wc = Wc0; dout = 128; din = 128; base = b; }
    else if (b < 640) { Ws = Ws1; Wb = Wb1; Wc = Wc1; dout = 128; din = 128; base = b - 320; }
    else { Ws = Ws2; Wb = Wb2; Wc = Wc2; dout = 47; din = 384; base = b - 640; }
    int idx = base * 256 + threadIdx.x;
    int kw = 5 * din;
    if (idx >= dout * kw) return;
    int n = idx / kw, c = idx % kw;
    float v;
    if (c < 4 * din) {
        int seg = c >> 9;
        int rem = c & 511;
        int g = rem >> 7;
        int dl = rem & 127;
        v = Ws[(size_t)n * 4 * din + 4 * (seg * 128 + dl) + g];
    } else {
        v = Wb[(size_t)n * din + (c - 4 * din)];
    }
    Wc[idx] = f2h(v);
}

// ---------------- per-row LN stats for f32 x (+ optional f16 mirror) ----------------

__global__ __launch_bounds__(256) void stats_f32(const float* __restrict__ X, float2* __restrict__ ST,
                                                 ushortT* __restrict__ xb, int n) {
    int wid = (blockIdx.x * 256 + threadIdx.x) >> 6;
    int lane = threadIdx.x & 63;
    if (wid >= n) return;
    float2 v = *(const float2*)(X + (size_t)wid * 128 + lane * 2);
    if (xb) {
        *(unsigned*)(xb + (size_t)wid * 128 + lane * 2) = pkrtz(v.x, v.y);
    }
    float s = v.x + v.y, ss = v.x * v.x + v.y * v.y;
    #pragma unroll
    for (int d = 1; d < 64; d <<= 1) { s += __shfl_xor(s, d); ss += __shfl_xor(ss, d); }
    if (lane == 0) ST[wid] = make_float2(s, ss);
}

// ---------------- CSR build: two-level counting sort ----------------
// Pack: src (bits 0..23, N < 2^24) | (dst & 255) << 24. Coarse bucket = dst >> 8.

__global__ __launch_bounds__(256) void zero_ints(int* p, int n) {
    int i = blockIdx.x * 256 + threadIdx.x;
    if (i < n) p[i] = 0;
}

__device__ __forceinline__ int wave_incl_scan(int v, int lane) {
    #pragma unroll
    for (int d = 1; d < 64; d <<= 1) {
        int o = __shfl_up(v, d);
        if (lane >= d) v += o;
    }
    return v;
}

// coarse histogram of dst>>8 (LDS-staged; ~nb global atomics per block)
__global__ __launch_bounds__(256) void coarse_hist(const int* __restrict__ dst, int* __restrict__ ghist,
                                                   int E, int nb) {
    __shared__ int h[512];
    for (int i = threadIdx.x; i < 512; i += 256) h[i] = 0;
    __syncthreads();
    int stride = gridDim.x * 256;
    for (int e = blockIdx.x * 256 + threadIdx.x; e < E; e += stride) {
        atomicAdd(&h[dst[e] >> 8], 1);
    }
    __syncthreads();
    for (int i = threadIdx.x; i < nb; i += 256) {
        int c = h[i];
        if (c) atomicAdd(&ghist[i], c);
    }
}

// exclusive scan of nb (<=512) bucket counts; writes base[0..nb] and a working copy gcur
__global__ __launch_bounds__(64) void bucket_scan(const int* __restrict__ ghist, int* __restrict__ base,
                                                  int* __restrict__ gcur, int nb) {
    int lane = threadIdx.x;
    int carry = 0;
    for (int b0 = 0; b0 < nb; b0 += 64) {
        int i = b0 + lane;
        int v = (i < nb) ? ghist[i] : 0;
        int incl = wave_incl_scan(v, lane);
        if (i < nb) { int ex = carry + incl - v; base[i] = ex; gcur[i] = ex; }
        carry += __shfl(incl, 63);
    }
    if (lane == 0) base[nb] = carry;
}

// bin edges into coarse buckets. Per block: LDS hist of its chunk, ONE global atomic per
// (block,bucket) to reserve a contiguous run, then LDS-cursor scatter -> runs of ~10 words.
#define SCAT_CH 4096
__global__ __launch_bounds__(256) void coarse_scatter(const int* __restrict__ src, const int* __restrict__ dst,
                                                      int* __restrict__ gcur, unsigned* __restrict__ pairs,
                                                      int E, int nb) {
    __shared__ int cur[512];
    for (int i = threadIdx.x; i < 512; i += 256) cur[i] = 0;
    __syncthreads();
    int e0 = blockIdx.x * SCAT_CH;
    int e1 = min(e0 + SCAT_CH, E);
    for (int e = e0 + threadIdx.x; e < e1; e += 256) atomicAdd(&cur[dst[e] >> 8], 1);
    __syncthreads();
    for (int i = threadIdx.x; i < nb; i += 256) {
        int c = cur[i];
        cur[i] = c ? atomicAdd(&gcur[i], c) : 0;
    }
    __syncthreads();
    for (int e = e0 + threadIdx.x; e < e1; e += 256) {
        int d = dst[e];
        int r = atomicAdd(&cur[d >> 8], 1);
        pairs[r] = (unsigned)src[e] | ((unsigned)(d & 255) << 24);
    }
}

// one block per coarse bucket: fine 256-bin hist -> rowptr + dinv, then scatter colv
// entirely inside the bucket's contiguous output window (full line utilization).
__global__ __launch_bounds__(256) void fine_csr(const unsigned* __restrict__ pairs, const int* __restrict__ base,
                                                int* __restrict__ rowptr, int* __restrict__ colv,
                                                float* __restrict__ dinv, int n, int E) {
    __shared__ int h[256];
    __shared__ int cur[256];
    __shared__ int wt[4];
    int b = blockIdx.x, tid = threadIdx.x;
    int e0 = base[b], e1 = base[b + 1];
    h[tid] = 0;
    __syncthreads();
    for (int e = e0 + tid; e < e1; e += 256) atomicAdd(&h[pairs[e] >> 24], 1);
    __syncthreads();
    int v = h[tid];
    int lane = tid & 63, w = tid >> 6;
    int incl = wave_incl_scan(v, lane);
    if (lane == 63) wt[w] = incl;
    __syncthreads();
    int woff = 0;
    for (int i = 0; i < w; i++) woff += wt[i];
    int excl = woff + incl - v;
    int node = b * 256 + tid;
    if (node < n) {
        rowptr[node] = e0 + excl;
        dinv[node] = rsqrtf((float)(v + 1));  // +1 self loop
        if (node == n - 1) rowptr[n] = E;
    }
    cur[tid] = e0 + excl;
    __syncthreads();
    for (int e = e0 + tid; e < e1; e += 256) {
        unsigned p = pairs[e];
        int r = atomicAdd(&cur[p >> 24], 1);
        colv[r] = (int)(p & 0x00FFFFFFu);
    }
}

// ---------------- fused FastKAN transform (f16 MFMA, packed-f16 math, X-prefetch) ----------------
// Block = 64 rows, 4 waves = 2 row-panels x 2 K-halves; each wave keeps 2 row-groups
// sharing each Wc B-fragment (r3) + K-split occupancy (r4) + single-pass RBF/SiLU (r6)
// + packed-f16 activation math (r7).
// Round-8: rolling 2-deep X prefetch (T14 issue-early). Chunk enumeration closed-form:
//   h = 0..NSEG*2-1, seg = h>>1 (compile-time), i = 2*(h&1)+kk. Chunk h+1's raw loads
//   issue BEFORE chunk h's compute; 2-slot register ring, indices fold after unroll
//   (rule #20). MFMA order unchanged -> bit-identical output.
template <int NSEG, int DOUT, int F32MASK>
__global__ __launch_bounds__(256) void fkan_kernel(
    const void* __restrict__ X0, int s0,
    const void* __restrict__ X1, int s1,
    const void* __restrict__ X2, int s2,
    const float2* __restrict__ ST0, const float2* __restrict__ ST1, const float2* __restrict__ ST2,
    const float* __restrict__ lng, const float* __restrict__ lnb,
    const ushortT* __restrict__ Wc,
    const float* __restrict__ bs, const float* __restrict__ bb,
    const float* __restrict__ dinv,
    ushortT* __restrict__ H, int hstride, int nrows) {
    constexpr int DIN = NSEG * 128;
    constexpr int KW = 5 * DIN;
    constexpr int NT = (DOUT + 15) / 16;
    constexpr int NCH = NSEG * 2;           // chunks per K-half
    constexpr bool ALLF16 = (F32MASK == 0);
    __shared__ float red[2][NT][4][64];  // [panel][tile][reg][lane]
    int tid = threadIdx.x;
    int w = tid >> 6, lane = tid & 63;
    int m = lane & 15, q = lane >> 4;
    int r = w & 1;    // row panel
    int kk = w >> 1;  // K half
    int baseA = blockIdx.x * 64 + r * 16;
    int baseB = baseA + 32;
    int rA = min(baseA + m, nrows - 1);
    int rB = min(baseB + m, nrows - 1);

    float muA, scA, muB, scB;
    {
        float2 st = ST0[rA]; float sum = st.x, ssq = st.y;
        if (NSEG == 3) { float2 t1 = ST1[rA]; sum += t1.x; ssq += t1.y; float2 t2 = ST2[rA]; sum += t2.x; ssq += t2.y; }
        muA = sum * (1.0f / DIN);
        float var = ssq * (1.0f / DIN) - muA * muA;
        scA = rsqrtf(fmaxf(var, 0.0f) + 1e-5f);
    }
    {
        float2 st = ST0[rB]; float sum = st.x, ssq = st.y;
        if (NSEG == 3) { float2 t1 = ST1[rB]; sum += t1.x; ssq += t1.y; float2 t2 = ST2[rB]; sum += t2.x; ssq += t2.y; }
        muB = sum * (1.0f / DIN);
        float var = ssq * (1.0f / DIN) - muB * muB;
        scB = rsqrtf(fmaxf(var, 0.0f) + 1e-5f);
    }

    float4v acc[NT][2];
    #pragma unroll
    for (int t = 0; t < NT; t++) {
        acc[t][0] = (float4v){0.f, 0.f, 0.f, 0.f};
        acc[t][1] = (float4v){0.f, 0.f, 0.f, 0.f};
    }

    // exp(-((z-G)*0.75)^2) == exp2(-(zc-Gc)^2), zc=z*CC, Gc=G*CC, CC=0.75*sqrt(log2 e)
    const float CC = 0.90084159f;
    const __half2 Gc2[4] = {
        __float2half2_rn(-2.f * CC), __float2half2_rn(-2.f / 3.f * CC),
        __float2half2_rn(2.f / 3.f * CC), __float2half2_rn(2.f * CC)};
    const __half2 NL2E = __float2half2_rn(-1.44269504f);
    const __half2 ONE2 = __float2half2_rn(1.0f);

    // ---- rolling 2-deep X prefetch ring (f16 path) ----
    uint4 rawA[2], rawB[2];
    if (ALLF16) {
        int d00 = kk * 32 + q * 8;  // h=0: seg=0, i=kk
        rawA[0] = *(const uint4*)((const ushortT*)X0 + (size_t)rA * s0 + d00);
        rawB[0] = *(const uint4*)((const ushortT*)X0 + (size_t)rB * s0 + d00);
    }

    #pragma unroll
    for (int h = 0; h < NCH; h++) {
        const int seg = h >> 1;                 // compile-time after unroll
        int i = 2 * (h & 1) + kk;
        int d0 = i * 32 + q * 8;
        float xa[8], xb8[8];
        uint4 curA, curB;
        if (ALLF16) {
            if (h + 1 < NCH) {                  // issue next chunk's loads EARLY
                const int seg2 = (h + 1) >> 1;
                int i2 = 2 * ((h + 1) & 1) + kk;
                int d2 = i2 * 32 + q * 8;
                const void* Xp2 = (seg2 == 0) ? X0 : (seg2 == 1) ? X1 : X2;
                int str2 = (seg2 == 0) ? s0 : (seg2 == 1) ? s1 : s2;
                rawA[(h + 1) & 1] = *(const uint4*)((const ushortT*)Xp2 + (size_t)rA * str2 + d2);
                rawB[(h + 1) & 1] = *(const uint4*)((const ushortT*)Xp2 + (size_t)rB * str2 + d2);
            }
            curA = rawA[h & 1];
            curB = rawB[h & 1];
            unpack8(curA, xa);
            unpack8(curB, xb8);
        } else {
            const void* Xp = (seg == 0) ? X0 : (seg == 1) ? X1 : X2;
            int str = (seg == 0) ? s0 : (seg == 1) ? s1 : s2;
            bool f32 = ((F32MASK >> seg) & 1) != 0;
            loadc8r(f32, Xp, (size_t)rA * str + d0, xa, curA);
            loadc8r(f32, Xp, (size_t)rB * str + d0, xb8, curB);
        }
        float4 gv0 = *(const float4*)(lng + seg * 128 + d0);
        float4 gv1 = *(const float4*)(lng + seg * 128 + d0 + 4);
        float4 bv0 = *(const float4*)(lnb + seg * 128 + d0);
        float4 bv1 = *(const float4*)(lnb + seg * 128 + d0 + 4);
        float gvs[8] = {gv0.x, gv0.y, gv0.z, gv0.w, gv1.x, gv1.y, gv1.z, gv1.w};
        float bvs[8] = {bv0.x, bv0.y, bv0.z, bv0.w, bv1.x, bv1.y, bv1.z, bv1.w};
        float za[8], zb[8];
        #pragma unroll
        for (int j = 0; j < 8; j++) {
            za[j] = (xa[j] - muA) * scA * gvs[j] + bvs[j];
            zb[j] = (xb8[j] - muB) * scB * gvs[j] + bvs[j];
        }
        // pack zc = z*CC
        __half2 zhA[4], zhB[4];
        #pragma unroll
        for (int p = 0; p < 4; p++) {
            zhA[p] = __builtin_bit_cast(__half2, pkrtz(za[2 * p] * CC, za[2 * p + 1] * CC));
            zhB[p] = __builtin_bit_cast(__half2, pkrtz(zb[2 * p] * CC, zb[2 * p + 1] * CC));
        }
        // RBF: 4 grid points, packed f16; exp output IS the fragment pair
        #pragma unroll
        for (int g = 0; g < 4; g++) {
            uint4v ua, ub;
            #pragma unroll
            for (int p = 0; p < 4; p++) {
                __half2 dA = __hsub2(zhA[p], Gc2[g]);
                ua[p] = __builtin_bit_cast(unsigned, h2exp2(__hmul2(dA, __hneg2(dA))));
                __half2 dB = __hsub2(zhB[p], Gc2[g]);
                ub[p] = __builtin_bit_cast(unsigned, h2exp2(__hmul2(dB, __hneg2(dB))));
            }
            f16x8 afa = __builtin_bit_cast(f16x8, ua);
            f16x8 afb = __builtin_bit_cast(f16x8, ub);
            int kbase = seg * 512 + g * 128 + i * 32;
            #pragma unroll
            for (int t = 0; t < NT; t++) {
                int n = t * 16 + m;
                f16x8 bfr = (f16x8)(_Float16)0;
                if ((DOUT % 16 == 0) || (n < DOUT))
                    bfr = *(const f16x8*)(Wc + (size_t)n * KW + kbase + q * 8);
                acc[t][0] = __builtin_amdgcn_mfma_f32_16x16x32_f16(afa, bfr, acc[t][0], 0, 0, 0);
                acc[t][1] = __builtin_amdgcn_mfma_f32_16x16x32_f16(afb, bfr, acc[t][1], 0, 0, 0);
            }
        }
        // SiLU from raw f16 pairs: x * 1/(1 + exp2(-x*log2e))
        {
            unsigned raA[4] = {curA.x, curA.y, curA.z, curA.w};
            unsigned raB[4] = {curB.x, curB.y, curB.z, curB.w};
            uint4v ua, ub;
            #pragma unroll
            for (int p = 0; p < 4; p++) {
                __half2 xhA = __builtin_bit_cast(__half2, raA[p]);
                __half2 sgA = h2rcp(__hadd2(ONE2, h2exp2(__hmul2(xhA, NL2E))));
                ua[p] = __builtin_bit_cast(unsigned, __hmul2(xhA, sgA));
                __half2 xhB = __builtin_bit_cast(__half2, raB[p]);
                __half2 sgB = h2rcp(__hadd2(ONE2, h2exp2(__hmul2(xhB, NL2E))));
                ub[p] = __builtin_bit_cast(unsigned, __hmul2(xhB, sgB));
            }
            f16x8 afa = __builtin_bit_cast(f16x8, ua);
            f16x8 afb = __builtin_bit_cast(f16x8, ub);
            int kbase = 4 * DIN + seg * 128 + i * 32;
            #pragma unroll
            for (int t = 0; t < NT; t++) {
                int n = t * 16 + m;
                f16x8 bfr = (f16x8)(_Float16)0;
                if ((DOUT % 16 == 0) || (n < DOUT))
                    bfr = *(const f16x8*)(Wc + (size_t)n * KW + kbase + q * 8);
                acc[t][0] = __builtin_amdgcn_mfma_f32_16x16x32_f16(afa, bfr, acc[t][0], 0, 0, 0);
                acc[t][1] = __builtin_amdgcn_mfma_f32_16x16x32_f16(afb, bfr, acc[t][1], 0, 0, 0);
            }
        }
    }

    // ---- cross-wave K-half reduction (2 barriers, self-ordered LDS reuse) ----
    if (kk == 1) {
        #pragma unroll
        for (int t = 0; t < NT; t++)
            #pragma unroll
            for (int j = 0; j < 4; j++) red[r][t][j][lane] = acc[t][0][j];
    }
    __syncthreads();
    if (kk == 0) {
        #pragma unroll
        for (int t = 0; t < NT; t++)
            #pragma unroll
            for (int j = 0; j < 4; j++) {
                acc[t][0][j] += red[r][t][j][lane];  // full group-A sum
                red[r][t][j][lane] = acc[t][1][j];   // hand B partial to the k=1 wave
            }
    }
    __syncthreads();
    if (kk == 1) {
        #pragma unroll
        for (int t = 0; t < NT; t++)
            #pragma unroll
            for (int j = 0; j < 4; j++) acc[t][1][j] += red[r][t][j][lane];  // full group-B sum
    }

    // ---- epilogue: kk=0 stores group A, kk=1 stores group B (C/D: col=lane&15, row=q*4+j) ----
    int gbase = (kk == 0) ? baseA : baseB;
    float dd[4];
    #pragma unroll
    for (int j = 0; j < 4; j++) {
        int row = gbase + q * 4 + j;
        dd[j] = (row < nrows) ? dinv[row] : 0.f;
    }
    if (kk == 0) {
        #pragma unroll
        for (int t = 0; t < NT; t++) {
            int col = t * 16 + m;
            if ((DOUT % 16 == 0) || (col < DOUT)) {
                float bias = bs[col] + bb[col];
                #pragma unroll
                for (int j = 0; j < 4; j++) {
                    int row = gbase + q * 4 + j;
                    if (row < nrows) H[(size_t)row * hstride + col] = f2h((acc[t][0][j] + bias) * dd[j]);
                }
            }
        }
    } else {
        #pragma unroll
        for (int t = 0; t < NT; t++) {
            int col = t * 16 + m;
            if ((DOUT % 16 == 0) || (col < DOUT)) {
                float bias = bs[col] + bb[col];
                #pragma unroll
                for (int j = 0; j < 4; j++) {
                    int row = gbase + q * 4 + j;
                    if (row < nrows) H[(size_t)row * hstride + col] = f2h((acc[t][1][j] + bias) * dd[j]);
                }
            }
        }
    }
}

// ---------------- aggregation: wave per node, 8 edge-streams in flight ----------------
// H (f16) is pre-scaled by dinv[src]. out = dinv[wid]*(H[wid] + sum_nbr H[s]) + bg.

__global__ __launch_bounds__(256) void agg128_kernel(
    const ushortT* __restrict__ H, ushortT* __restrict__ OUT,
    const float* __restrict__ bg, const int* __restrict__ rowptr,
    const int* __restrict__ colv, const float* __restrict__ dinv,
    float2* __restrict__ STout, int n) {
    int wid = (blockIdx.x * 256 + threadIdx.x) >> 6;
    int lane = threadIdx.x & 63;
    if (wid >= n) return;
    int g = lane >> 4, t = lane & 15;
    float di = dinv[wid];
    float a[8] = {0.f, 0.f, 0.f, 0.f, 0.f, 0.f, 0.f, 0.f};
    if (g == 0) unpack_add(*(const uint4*)(H + (size_t)wid * 128 + t * 8), a);  // self
    int e0 = rowptr[wid], e1 = rowptr[wid + 1];
    int e = e0 + g;
    for (; e + 4 < e1; e += 8) {
        int s0i = colv[e], s1i = colv[e + 4];
        uint4 v0 = *(const uint4*)(H + (size_t)s0i * 128 + t * 8);
        uint4 v1 = *(const uint4*)(H + (size_t)s1i * 128 + t * 8);
        unpack_add(v0, a);
        unpack_add(v1, a);
    }
    if (e < e1) {
        unpack_add(*(const uint4*)(H + (size_t)colv[e] * 128 + t * 8), a);
    }
    #pragma unroll
    for (int j = 0; j < 8; j++) {
        a[j] += __shfl_xor(a[j], 16);
        a[j] += __shfl_xor(a[j], 32);
    }
    if (g == 0) {
        float4 b0 = *(const float4*)(bg + t * 8);
        float4 b1 = *(const float4*)(bg + t * 8 + 4);
        float bgs[8] = {b0.x, b0.y, b0.z, b0.w, b1.x, b1.y, b1.z, b1.w};
        unsigned rb[8];
        float s = 0.f, ss = 0.f;
        #pragma unroll
        for (int j = 0; j < 8; j++) {
            float o = di * a[j] + bgs[j];
            rb[j] = f2h(o);                       // RTNE; stored value
            float back = h2f((unsigned short)rb[j]);
            s += back; ss += back * back;         // stats of STORED values (LN consistency)
        }
        uint4 pk;
        pk.x = rb[0] | (rb[1] << 16);
        pk.y = rb[2] | (rb[3] << 16);
        pk.z = rb[4] | (rb[5] << 16);
        pk.w = rb[6] | (rb[7] << 16);
        *(uint4*)(OUT + (size_t)wid * 128 + t * 8) = pk;
        #pragma unroll
        for (int d = 1; d < 16; d <<= 1) { s += __shfl_xor(s, d); ss += __shfl_xor(ss, d); }
        if (t == 0) STout[wid] = make_float2(s, ss);
    }
}

// H stride 64 (cols 47..63 junk, never written out). 16 edge-streams in flight.
__global__ __launch_bounds__(256) void agg47_kernel(
    const ushortT* __restrict__ H, float* __restrict__ OUT,
    const float* __restrict__ bg, const int* __restrict__ rowptr,
    const int* __restrict__ colv, const float* __restrict__ dinv, int n) {
    int wid = (blockIdx.x * 256 + threadIdx.x) >> 6;
    int lane = threadIdx.x & 63;
    if (wid >= n) return;
    int g = lane >> 3, t = lane & 7;
    float di = dinv[wid];
    float a[8] = {0.f, 0.f, 0.f, 0.f, 0.f, 0.f, 0.f, 0.f};
    if (g == 0) unpack_add(*(const uint4*)(H + (size_t)wid * 64 + t * 8), a);  // self
    int e0 = rowptr[wid], e1 = rowptr[wid + 1];
    int e = e0 + g;
    for (; e + 8 < e1; e += 16) {
        int s0i = colv[e], s1i = colv[e + 8];
        uint4 v0 = *(const uint4*)(H + (size_t)s0i * 64 + t * 8);
        uint4 v1 = *(const uint4*)(H + (size_t)s1i * 64 + t * 8);
        unpack_add(v0, a);
        unpack_add(v1, a);
    }
    if (e < e1) {
        unpack_add(*(const uint4*)(H + (size_t)colv[e] * 64 + t * 8), a);
    }
    #pragma unroll
    for (int j = 0; j < 8; j++) {
        a[j] += __shfl_xor(a[j], 8);
        a[j] += __shfl_xor(a[j], 16);
        a[j] += __shfl_xor(a[j], 32);
    }
    if (g == 0) {
        #pragma unroll
        for (int j = 0; j < 8; j++) {
            int c = t * 8 + j;
            if (c < 47) OUT[(size_t)wid * 47 + c] = di * a[j] + bg[c];
        }
    }
}

// ---------------- launcher ----------------

extern "C" void kernel_launch(void* const* d_in, const int* in_sizes, int n_in,
                              void* d_out, int out_size, void* d_ws, size_t ws_size,
                              hipStream_t stream) {
    const float* x = (const float*)d_in[0];
    const int* ei = (const int*)d_in[1];
    const float* lng0 = (const float*)d_in[2];
    const float* lnb0 = (const float*)d_in[3];
    const float* Ws0 = (const float*)d_in[4];
    const float* bs0 = (const float*)d_in[5];
    const float* Wb0 = (const float*)d_in[6];
    const float* bb0 = (const float*)d_in[7];
    const float* bg0 = (const float*)d_in[8];
    const float* lng1 = (const float*)d_in[9];
    const float* lnb1 = (const float*)d_in[10];
    const float* Ws1 = (const float*)d_in[11];
    const float* bs1 = (const float*)d_in[12];
    const float* Wb1 = (const float*)d_in[13];
    const float* bb1 = (const float*)d_in[14];
    const float* bg1 = (const float*)d_in[15];
    const float* lng2 = (const float*)d_in[16];
    const float* lnb2 = (const float*)d_in[17];
    const float* Ws2 = (const float*)d_in[18];
    const float* bs2 = (const float*)d_in[19];
    const float* Wb2 = (const float*)d_in[20];
    const float* bb2 = (const float*)d_in[21];
    const float* bg2 = (const float*)d_in[22];

    const int N = in_sizes[0] / 128;
    const int E = in_sizes[1] / 2;
    const int NB = (N + 255) >> 8;  // coarse buckets of 256 nodes (requires N < 2^24)

    char* wsp = (char*)d_ws;
    size_t off = 0;
    auto alloc = [&](size_t bytes) {
        off = (off + 255) & ~(size_t)255;
        void* p = wsp + off;
        off += bytes;
        return p;
    };
    int* ghist = (int*)alloc(512 * 4);
    int* bbase = (int*)alloc(513 * 4);
    int* gcur = (int*)alloc(512 * 4);
    int* rowptr = (int*)alloc((size_t)(N + 1) * 4);
    int* colv = (int*)alloc((size_t)E * 4);
    float* dinvv = (float*)alloc((size_t)N * 4);
    ushortT* hbuf = (ushortT*)alloc((size_t)N * 128 * 2);
    ushortT* a1 = (ushortT*)alloc((size_t)N * 128 * 2);
    ushortT* a2 = (ushortT*)alloc((size_t)N * 128 * 2);
    float2* stx = (float2*)alloc((size_t)N * 8);
    float2* st1 = (float2*)alloc((size_t)N * 8);
    float2* st2 = (float2*)alloc((size_t)N * 8);
    ushortT* Wc0 = (ushortT*)alloc((size_t)128 * 640 * 2);
    ushortT* Wc1 = (ushortT*)alloc((size_t)128 * 640 * 2);
    ushortT* Wc2 = (ushortT*)alloc((size_t)47 * 1920 * 2);
    size_t off_base = off;
    ushortT* xb = (ushortT*)alloc((size_t)N * 128 * 2);  // f16 mirror of x
    bool fits = (off <= ws_size);
    if (!fits) off = off_base;
    (void)n_in; (void)out_size;

    // pairs staging aliases hbuf: pairs is dead before the first fkan writes hbuf.
    unsigned* pairs = (unsigned*)hbuf;

    const int* srcp = ei;
    const int* dstp = ei + E;

    int gF = (N + 63) / 64;
    int gW = (N + 3) / 4;
    int gScat = (E + SCAT_CH - 1) / SCAT_CH;

    // single launch builds all three Wc (320 + 320 + 353 blocks)
    build_wc3<<<993, 256, 0, stream>>>(Ws0, Wb0, Wc0, Ws1, Wb1, Wc1, Ws2, Wb2, Wc2);

    // CSR build: coarse hist -> scan -> coarse scatter (packed pairs) -> fine per-bucket CSR
    zero_ints<<<2, 256, 0, stream>>>(ghist, 512);
    coarse_hist<<<NB, 256, 0, stream>>>(dstp, ghist, E, NB);
    bucket_scan<<<1, 64, 0, stream>>>(ghist, bbase, gcur, NB);
    coarse_scatter<<<gScat, 256, 0, stream>>>(srcp, dstp, gcur, pairs, E, NB);
    fine_csr<<<NB, 256, 0, stream>>>(pairs, bbase, rowptr, colv, dinvv, N, E);

    stats_f32<<<gW, 256, 0, stream>>>(x, stx, fits ? xb : nullptr, N);

    // layer 1
    if (fits)
        fkan_kernel<1, 128, 0><<<gF, 256, 0, stream>>>(xb, 128, xb, 128, xb, 128, stx, stx, stx,
                                                       lng0, lnb0, Wc0, bs0, bb0, dinvv, hbuf, 128, N);
    else
        fkan_kernel<1, 128, 1><<<gF, 256, 0, stream>>>(x, 128, x, 128, x, 128, stx, stx, stx,
                                                       lng0, lnb0, Wc0, bs0, bb0, dinvv, hbuf, 128, N);
    agg128_kernel<<<gW, 256, 0, stream>>>(hbuf, a1, bg0, rowptr, colv, dinvv, st1, N);

    // layer 2
    fkan_kernel<1, 128, 0><<<gF, 256, 0, stream>>>(a1, 128, a1, 128, a1, 128, st1, st1, st1,
                                                   lng1, lnb1, Wc1, bs1, bb1, dinvv, hbuf, 128, N);
    agg128_kernel<<<gW, 256, 0, stream>>>(hbuf, a2, bg1, rowptr, colv, dinvv, st2, N);

    // layer 3 (hbuf stride 64)
    if (fits)
        fkan_kernel<3, 47, 0><<<gF, 256, 0, stream>>>(xb, 128, a1, 128, a2, 128, stx, st1, st2,
                                                      lng2, lnb2, Wc2, bs2, bb2, dinvv, hbuf, 64, N);
    else
        fkan_kernel<3, 47, 1><<<gF, 256, 0, stream>>>(x, 128, a1, 128, a2, 128, stx, st1, st2,
                                                      lng2, lnb2, Wc2, bs2, bb2, dinvv, hbuf, 64, N);
    agg47_kernel<<<gW, 256, 0, stream>>>(hbuf, (float*)d_out, bg2, rowptr, colv, dinvv, N);
}